// Round 3
// baseline (543.861 us; speedup 1.0000x reference)
//
#include <hip/hip_runtime.h>
#include <math.h>

#define B_      2
#define N_      4096
#define H_      1024
#define HEADS_  16
#define DH_     64
#define M_      256
#define NSPLIT  8
#define EPAD    80

constexpr float NORMALIZER = 0.35355339059327373f; // 64^-0.25
constexpr float RATIO      = 0.0625f;              // 256^-0.5
constexpr float KEPS       = 1e-3f;

typedef __bf16 bf16x8 __attribute__((ext_vector_type(8)));
typedef __bf16 bf16x4 __attribute__((ext_vector_type(4)));
typedef float  f32x4  __attribute__((ext_vector_type(4)));

// ======================================================================
// Split fp32 -> bf16 (hi, lo)
// ======================================================================
__global__ __launch_bounds__(256) void split_bf16(
    const float* __restrict__ src, __bf16* __restrict__ hi, __bf16* __restrict__ lo)
{
    int i = blockIdx.x * 256 + threadIdx.x;
    float4 v = ((const float4*)src)[i];
    float vv[4] = {v.x, v.y, v.z, v.w};
    bf16x4 h, l;
#pragma unroll
    for (int j = 0; j < 4; ++j) {
        __bf16 hh = (__bf16)vv[j];
        h[j] = hh;
        l[j] = (__bf16)(vv[j] - (float)hh);
    }
    ((bf16x4*)hi)[i] = h;
    ((bf16x4*)lo)[i] = l;
}

__global__ __launch_bounds__(256) void split_w(
    const float* __restrict__ W0, const float* __restrict__ W1,
    const float* __restrict__ W2, const float* __restrict__ W3,
    __bf16* __restrict__ hi, __bf16* __restrict__ lo)
{
    const float* src = W0;
    if (blockIdx.y == 1) src = W1;
    else if (blockIdx.y == 2) src = W2;
    else if (blockIdx.y == 3) src = W3;
    int i = blockIdx.x * 256 + threadIdx.x;
    size_t o = (size_t)blockIdx.y * 262144 + i;
    float4 v = ((const float4*)src)[i];
    float vv[4] = {v.x, v.y, v.z, v.w};
    bf16x4 h, l;
#pragma unroll
    for (int j = 0; j < 4; ++j) {
        __bf16 hh = (__bf16)vv[j];
        h[j] = hh;
        l[j] = (__bf16)(vv[j] - (float)hh);
    }
    ((bf16x4*)hi)[o] = h;
    ((bf16x4*)lo)[o] = l;
}

// ======================================================================
// Split-bf16 MFMA GEMM, C = A@W^T + bias. BF16OUT: write C as bf16 hi/lo.
// 512 threads / 8 waves, wave tile 64x32. 4-phase / K-tile schedule
// (T3+T4+T5, half-tile staging granularity):
//   - BK=64 K-tiles, double-buffered; each tile split in 2 ks-halves of
//     32 cols. LDS [2buf][4 tiles][2 ks][128][32] = 128 KiB, 1 blk/CU.
//   - per K-tile 4 phases = (ks, i-half) quadrants of 12 MFMAs. Each
//     phase: [vmcnt(4) at ks boundary] barrier; ds_read frags (8 or 4);
//     issue 2 global_load_lds; lgkmcnt(0)+sched_barrier; setprio(1);
//     12 MFMA; setprio(0).
//   - counted vmcnt(4) retires exactly one half-tile; 8 loads stay in
//     flight in steady state, NEVER drained to 0 in the loop (T4).
//   - last tile stages kt=0 into the dead buffer (keeps counts uniform).
//   - XOR swizzle on global source chunk + ds_read address (rule #21),
//     identical per-half to the verified round-1/2 kernel: conflict-free.
// ======================================================================
template<bool BF16OUT>
__global__ __launch_bounds__(512, 2) void gemm_mfma3(
    const __bf16* __restrict__ Ah, const __bf16* __restrict__ Al,
    const __bf16* __restrict__ Bh0, const __bf16* __restrict__ Bl0,
    const __bf16* __restrict__ Bh1, const __bf16* __restrict__ Bl1,
    const __bf16* __restrict__ Bh2, const __bf16* __restrict__ Bl2,
    const float* __restrict__ bi0, const float* __restrict__ bi1, const float* __restrict__ bi2,
    float* __restrict__ C0,
    __bf16* __restrict__ Ch0, __bf16* __restrict__ Cl0,
    __bf16* __restrict__ Ch1, __bf16* __restrict__ Cl1,
    __bf16* __restrict__ Ch2, __bf16* __restrict__ Cl2)
{
    const __bf16* Bh = Bh0; const __bf16* Bl = Bl0; const float* bias = bi0;
    __bf16* Ch = Ch0; __bf16* Cl = Cl0;
    if (blockIdx.z == 1) { Bh = Bh1; Bl = Bl1; bias = bi1; Ch = Ch1; Cl = Cl1; }
    else if (blockIdx.z == 2) { Bh = Bh2; Bl = Bl2; bias = bi2; Ch = Ch2; Cl = Cl2; }

    // [buf][tile][ks][128*32]; tile: 0=Ah 1=Al 2=Bh 3=Bl
    __shared__ alignas(16) __bf16 lds[2][4][2][128 * 32];

    const int t    = threadIdx.x;
    const int lane = t & 63;
    const int lm   = lane & 15;
    const int lq   = lane >> 4;
    const int w    = t >> 6;
    const int wm   = (w >> 2) * 64;    // m half
    const int wn   = (w & 3) * 32;     // n quarter
    const int m0   = blockIdx.y * 128;
    const int n0   = blockIdx.x * 128;
    const int K    = 1024;
    const int NT   = 16;               // K-tiles of 64

    // staging: wave w owns tile tw = w>>1, row-half hw = w&1 (rows hw*64..+63).
    // Per ks-half: 4 calls x 1KiB; call c covers rows hw*64+c*16 .. +15.
    // lane -> rsub = lane>>2 (16 rows), slot = lane&3 (4 chunks of 8 cols).
    // Global col chunk pre-swizzled: schunk = slot ^ ((lane>>3)&3)
    // ((row>>1)&3 == (lane>>3)&3 since hw*64, c*16 don't touch bits 1-2).
    const int tw = w >> 1;
    const int hw = w & 1;
    const __bf16* mysrc = (tw == 0) ? Ah : (tw == 1) ? Al : (tw == 2) ? Bh : Bl;
    const int     rbase = ((tw < 2) ? m0 : n0) + hw * 64;
    const int rsub   = lane >> 2;
    const int slot   = lane & 3;
    const int schunk = slot ^ ((lane >> 3) & 3);
    const __bf16* gbase = mysrc + (size_t)(rbase + rsub) * K + schunk * 8;

    f32x4 acc[4][2];
#pragma unroll
    for (int i = 0; i < 4; ++i)
#pragma unroll
        for (int j = 0; j < 2; ++j) acc[i][j] = (f32x4){0.f, 0.f, 0.f, 0.f};

    // read-side swizzle (same involution, lane-constant)
    const int swz = (lq ^ ((lm >> 1) & 3)) * 8;

    // one 1KiB DMA: half ks of K-tile kt, call c, into buffer buf
    auto stageCall = [&](int buf, int kt, int ks, int c) {
        const __bf16* g = gbase + (size_t)(c * 16) * K + kt * 64 + ks * 32;
        __builtin_amdgcn_global_load_lds(
            (const __attribute__((address_space(1))) void*)g,
            (__attribute__((address_space(3))) void*)&lds[buf][tw][ks][(hw * 64 + c * 16) * 32],
            16, 0, 0);
    };

#define MFMA3(ACC, AH, AL, BHF, BLF) \
    ACC = __builtin_amdgcn_mfma_f32_16x16x32_bf16(AH, BHF, ACC, 0, 0, 0); \
    ACC = __builtin_amdgcn_mfma_f32_16x16x32_bf16(AL, BHF, ACC, 0, 0, 0); \
    ACC = __builtin_amdgcn_mfma_f32_16x16x32_bf16(AH, BLF, ACC, 0, 0, 0);

    // prologue: stage tile 0 (both halves) into buf 0
#pragma unroll
    for (int c = 0; c < 4; ++c) stageCall(0, 0, 0, c);
#pragma unroll
    for (int c = 0; c < 4; ++c) stageCall(0, 0, 1, c);

#pragma unroll 1
    for (int kt = 0; kt < NT; ++kt) {
        const int p  = kt & 1;
        const int nb = p ^ 1;
        const int nk = (kt + 1) & 15;          // clamp: last tile re-stages kt=0 (dead buffer)
        bf16x8 bh[2], bl[2], ah[2], al[2];

        // ---- phase q0: ks=0, i in {0,1} ----
        asm volatile("s_waitcnt vmcnt(4)" ::: "memory");   // (kt,ks0) landed (mine)
        asm volatile("s_barrier" ::: "memory");            // everyone's landed
#pragma unroll
        for (int j = 0; j < 2; ++j) {
            int off = (wn + j * 16 + lm) * 32 + swz;
            bh[j] = *(const bf16x8*)&lds[p][2][0][off];
            bl[j] = *(const bf16x8*)&lds[p][3][0][off];
        }
#pragma unroll
        for (int i = 0; i < 2; ++i) {
            int off = (wm + i * 16 + lm) * 32 + swz;
            ah[i] = *(const bf16x8*)&lds[p][0][0][off];
            al[i] = *(const bf16x8*)&lds[p][1][0][off];
        }
        stageCall(nb, nk, 0, 0); stageCall(nb, nk, 0, 1);
        asm volatile("s_waitcnt lgkmcnt(0)" ::: "memory");
        __builtin_amdgcn_sched_barrier(0);
        __builtin_amdgcn_s_setprio(1);
#pragma unroll
        for (int i = 0; i < 2; ++i)
#pragma unroll
            for (int j = 0; j < 2; ++j) { MFMA3(acc[i][j], ah[i], al[i], bh[j], bl[j]); }
        __builtin_amdgcn_s_setprio(0);

        // ---- phase q1: ks=0, i in {2,3} ----
        asm volatile("s_barrier" ::: "memory");
#pragma unroll
        for (int i = 0; i < 2; ++i) {
            int off = (wm + (i + 2) * 16 + lm) * 32 + swz;
            ah[i] = *(const bf16x8*)&lds[p][0][0][off];
            al[i] = *(const bf16x8*)&lds[p][1][0][off];
        }
        stageCall(nb, nk, 0, 2); stageCall(nb, nk, 0, 3);
        asm volatile("s_waitcnt lgkmcnt(0)" ::: "memory");
        __builtin_amdgcn_sched_barrier(0);
        __builtin_amdgcn_s_setprio(1);
#pragma unroll
        for (int i = 0; i < 2; ++i)
#pragma unroll
            for (int j = 0; j < 2; ++j) { MFMA3(acc[i + 2][j], ah[i], al[i], bh[j], bl[j]); }
        __builtin_amdgcn_s_setprio(0);

        // ---- phase q2: ks=1, i in {0,1} ----
        asm volatile("s_waitcnt vmcnt(4)" ::: "memory");   // (kt,ks1) landed (mine)
        asm volatile("s_barrier" ::: "memory");
#pragma unroll
        for (int j = 0; j < 2; ++j) {
            int off = (wn + j * 16 + lm) * 32 + swz;
            bh[j] = *(const bf16x8*)&lds[p][2][1][off];
            bl[j] = *(const bf16x8*)&lds[p][3][1][off];
        }
#pragma unroll
        for (int i = 0; i < 2; ++i) {
            int off = (wm + i * 16 + lm) * 32 + swz;
            ah[i] = *(const bf16x8*)&lds[p][0][1][off];
            al[i] = *(const bf16x8*)&lds[p][1][1][off];
        }
        stageCall(nb, nk, 1, 0); stageCall(nb, nk, 1, 1);
        asm volatile("s_waitcnt lgkmcnt(0)" ::: "memory");
        __builtin_amdgcn_sched_barrier(0);
        __builtin_amdgcn_s_setprio(1);
#pragma unroll
        for (int i = 0; i < 2; ++i)
#pragma unroll
            for (int j = 0; j < 2; ++j) { MFMA3(acc[i][j], ah[i], al[i], bh[j], bl[j]); }
        __builtin_amdgcn_s_setprio(0);

        // ---- phase q3: ks=1, i in {2,3} ----
        asm volatile("s_barrier" ::: "memory");
#pragma unroll
        for (int i = 0; i < 2; ++i) {
            int off = (wm + (i + 2) * 16 + lm) * 32 + swz;
            ah[i] = *(const bf16x8*)&lds[p][0][1][off];
            al[i] = *(const bf16x8*)&lds[p][1][1][off];
        }
        stageCall(nb, nk, 1, 2); stageCall(nb, nk, 1, 3);
        asm volatile("s_waitcnt lgkmcnt(0)" ::: "memory");
        __builtin_amdgcn_sched_barrier(0);
        __builtin_amdgcn_s_setprio(1);
#pragma unroll
        for (int i = 0; i < 2; ++i)
#pragma unroll
            for (int j = 0; j < 2; ++j) { MFMA3(acc[i + 2][j], ah[i], al[i], bh[j], bl[j]); }
        __builtin_amdgcn_s_setprio(0);
    }
    asm volatile("s_waitcnt vmcnt(0)" ::: "memory");       // drain stray clamp loads
#undef MFMA3

    float bsr[2];
#pragma unroll
    for (int j = 0; j < 2; ++j) bsr[j] = bias[n0 + wn + j * 16 + lm];
#pragma unroll
    for (int i = 0; i < 4; ++i)
#pragma unroll
        for (int r = 0; r < 4; ++r) {
            int rowm = m0 + wm + i * 16 + lq * 4 + r;
#pragma unroll
            for (int j = 0; j < 2; ++j) {
                int col = n0 + wn + j * 16 + lm;
                float o = acc[i][j][r] + bsr[j];
                if (BF16OUT) {
                    __bf16 hh = (__bf16)o;
                    Ch[(size_t)rowm * 1024 + col] = hh;
                    Cl[(size_t)rowm * 1024 + col] = (__bf16)(o - (float)hh);
                } else {
                    C0[(size_t)rowm * 1024 + col] = o;
                }
            }
        }
}

// ======================================================================
// diag_k from bf16 hi/lo K
// ======================================================================
__global__ __launch_bounds__(256) void diag_kernel(
    const __bf16* __restrict__ Kh, const __bf16* __restrict__ Kl,
    float* __restrict__ diag, float* __restrict__ partials)
{
    int gt = blockIdx.x * 256 + threadIdx.x;
    int r  = gt >> 2;
    int q  = gt & 3;
    const bf16x8* ph = (const bf16x8*)(Kh + (size_t)r * 64 + q * 16);
    const bf16x8* pl = (const bf16x8*)(Kl + (size_t)r * 64 + q * 16);
    float s = 0.f;
#pragma unroll
    for (int i = 0; i < 2; ++i) {
        bf16x8 vh = ph[i], vl = pl[i];
#pragma unroll
        for (int j = 0; j < 8; ++j) {
            float x = (float)vh[j] + (float)vl[j];
            s += x * x;
        }
    }
    s += __shfl_xor(s, 1);
    s += __shfl_xor(s, 2);
    float d = -0.5f * s;
    if (q == 0) {
        int h = r & 15, bn = r >> 4;
        int n = bn & 4095, b = bn >> 12;
        diag[(((size_t)b * 16 + h) << 12) + n] = d;
    }
    __shared__ float red[256];
    red[threadIdx.x] = d;
    __syncthreads();
    for (int s2 = 128; s2 > 0; s2 >>= 1) {
        if (threadIdx.x < s2) red[threadIdx.x] = fmaxf(red[threadIdx.x], red[threadIdx.x + s2]);
        __syncthreads();
    }
    if (threadIdx.x == 0) partials[blockIdx.x] = red[0];
}

__global__ __launch_bounds__(256) void reduce_stab(
    const float* __restrict__ partials, float* __restrict__ stab, int n)
{
    float m = -3.0e38f;
    for (int i = threadIdx.x; i < n; i += 256) m = fmaxf(m, partials[i]);
    __shared__ float red[256];
    red[threadIdx.x] = m;
    __syncthreads();
    for (int s2 = 128; s2 > 0; s2 >>= 1) {
        if (threadIdx.x < s2) red[threadIdx.x] = fmaxf(red[threadIdx.x], red[threadIdx.x + s2]);
        __syncthreads();
    }
    if (threadIdx.x == 0) stab[0] = red[0];
}

// ======================================================================
// ctx via MFMA. grid (NSPLIT, 2 m-halves, 32 bh). 4 waves, wave owns 32 m.
// dash: D[n64, m32/wave] = K@proj^T (3 split products, operands from global)
// exp -> kf bf16 hi/lo -> LDS transpose kfT[m][n] -> ctx += kfT @ vT[e][n]
// e=64 is ones (k_cumsum); e 65..79 zero pad. fp32 partials out [s][bh][e][m].
// ======================================================================
__global__ __launch_bounds__(256) void ctx_mfma(
    const __bf16* __restrict__ Kh, const __bf16* __restrict__ Kl,
    const __bf16* __restrict__ Vh, const __bf16* __restrict__ Vl,
    const __bf16* __restrict__ projH, const __bf16* __restrict__ projL,
    const float* __restrict__ diag, const float* __restrict__ stabp,
    float* __restrict__ ctxp)
{
    __shared__ alignas(16) char ldsbuf[59904];
    __shared__ float dg[64];
    __bf16* kfTh = (__bf16*)ldsbuf;              // [128][72]
    __bf16* kfTl = kfTh + 9216;                  // [128][72]
    __bf16* vTh  = kfTl + 9216;                  // [80][72]
    __bf16* vTl  = vTh + 5760;                   // [80][72]
    float*  ctxe = (float*)ldsbuf;               // [128][81] (epilogue alias)

    const int t    = threadIdx.x;
    const int lane = t & 63;
    const int w    = t >> 6;
    const int lm   = lane & 15;
    const int lq   = lane >> 4;
    const int bh   = blockIdx.z;
    const int b    = bh >> 4, h = bh & 15;
    const int mh   = blockIdx.y;
    const int slice = blockIdx.x;
    const int mwave = mh * 128 + w * 32;          // global m base for wave
    const float stab = stabp[0];
    const size_t rowbase = (size_t)b * N_ * H_ + (size_t)h * DH_;
    const float* diag_bh = diag + (size_t)bh * N_;

    // vT constant rows: e=64 -> ones (hi), e>64 -> zero
    for (int idx = t; idx < 16 * 72; idx += 256) {
        int e = 64 + idx / 72, n = idx % 72;
        vTh[e * 72 + n] = (e == 64 && n < 64) ? (__bf16)1.0f : (__bf16)0.0f;
        vTl[e * 72 + n] = (__bf16)0.0f;
    }

    // proj B-frags, register-cached for whole kernel: [mf][ks]
    bf16x8 ph[2][2], pl[2][2];
#pragma unroll
    for (int mf = 0; mf < 2; ++mf)
#pragma unroll
        for (int ks = 0; ks < 2; ++ks) {
            size_t pa = (size_t)(mwave + mf * 16 + lm) * 64 + ks * 32 + lq * 8;
            ph[mf][ks] = *(const bf16x8*)(projH + pa);
            pl[mf][ks] = *(const bf16x8*)(projL + pa);
        }

    f32x4 acc[2][5];
#pragma unroll
    for (int mf = 0; mf < 2; ++mf)
#pragma unroll
        for (int ef = 0; ef < 5; ++ef) acc[mf][ef] = (f32x4){0.f, 0.f, 0.f, 0.f};

    for (int tile = 0; tile < 8; ++tile) {
        const int n0 = slice * (N_ / NSPLIT) + tile * 64;
        __syncthreads();   // barrier A: prior GEMM reads of vT done

        // stage vT rows 0..63 (transpose V[n][d] -> vT[d][n])
        {
            int nl = t >> 2, dc = (t & 3) * 16;
            size_t va = rowbase + (size_t)(n0 + nl) * H_ + dc;
            bf16x8 v0 = *(const bf16x8*)(Vh + va);
            bf16x8 v1 = *(const bf16x8*)(Vh + va + 8);
            bf16x8 u0 = *(const bf16x8*)(Vl + va);
            bf16x8 u1 = *(const bf16x8*)(Vl + va + 8);
#pragma unroll
            for (int j = 0; j < 8; ++j) {
                vTh[(dc + j) * 72 + nl]     = v0[j];
                vTh[(dc + 8 + j) * 72 + nl] = v1[j];
                vTl[(dc + j) * 72 + nl]     = u0[j];
                vTl[(dc + 8 + j) * 72 + nl] = u1[j];
            }
        }
        if (t < 64) dg[t] = diag_bh[n0 + t] - stab;

        // dash MFMA (global operands, no LDS dependency)
        f32x4 dsh[4][2];
#pragma unroll
        for (int nf = 0; nf < 4; ++nf) {
#pragma unroll
            for (int mf = 0; mf < 2; ++mf) dsh[nf][mf] = (f32x4){0.f, 0.f, 0.f, 0.f};
            bf16x8 ah[2], al[2];
#pragma unroll
            for (int ks = 0; ks < 2; ++ks) {
                size_t ka = rowbase + (size_t)(n0 + nf * 16 + lm) * H_ + ks * 32 + lq * 8;
                ah[ks] = *(const bf16x8*)(Kh + ka);
                al[ks] = *(const bf16x8*)(Kl + ka);
            }
#pragma unroll
            for (int mf = 0; mf < 2; ++mf)
#pragma unroll
                for (int ks = 0; ks < 2; ++ks) {
                    dsh[nf][mf] = __builtin_amdgcn_mfma_f32_16x16x32_bf16(ah[ks], ph[mf][ks], dsh[nf][mf], 0, 0, 0);
                    dsh[nf][mf] = __builtin_amdgcn_mfma_f32_16x16x32_bf16(al[ks], ph[mf][ks], dsh[nf][mf], 0, 0, 0);
                    dsh[nf][mf] = __builtin_amdgcn_mfma_f32_16x16x32_bf16(ah[ks], pl[mf][ks], dsh[nf][mf], 0, 0, 0);
                }
        }

        __syncthreads();   // barrier B: vT + dg staged

        // exp -> kf bf16 hi/lo -> kfT (wave-private rows)
#pragma unroll
        for (int nf = 0; nf < 4; ++nf) {
            float4 dgv = *(const float4*)&dg[nf * 16 + lq * 4];
            float dga[4] = {dgv.x, dgv.y, dgv.z, dgv.w};
#pragma unroll
            for (int mf = 0; mf < 2; ++mf) {
                int mrow = w * 32 + mf * 16 + lm;   // block-local m row
#pragma unroll
                for (int r = 0; r < 4; ++r) {
                    float kf = RATIO * (__expf(dga[r] + NORMALIZER * dsh[nf][mf][r]) + KEPS);
                    __bf16 hh = (__bf16)kf;
                    int nloc = nf * 16 + lq * 4 + r;
                    kfTh[mrow * 72 + nloc] = hh;
                    kfTl[mrow * 72 + nloc] = (__bf16)(kf - (float)hh);
                }
            }
        }

        // ctx accumulate: acc[mf][ef] += kfT[m][n] @ vT[e][n]
#pragma unroll
        for (int ks = 0; ks < 2; ++ks) {
#pragma unroll
            for (int mf = 0; mf < 2; ++mf) {
                bf16x8 af = *(const bf16x8*)&kfTh[(w * 32 + mf * 16 + lm) * 72 + ks * 32 + lq * 8];
                bf16x8 afl = *(const bf16x8*)&kfTl[(w * 32 + mf * 16 + lm) * 72 + ks * 32 + lq * 8];
#pragma unroll
                for (int ef = 0; ef < 5; ++ef) {
                    bf16x8 bfh = *(const bf16x8*)&vTh[(ef * 16 + lm) * 72 + ks * 32 + lq * 8];
                    bf16x8 bfl = *(const bf16x8*)&vTl[(ef * 16 + lm) * 72 + ks * 32 + lq * 8];
                    acc[mf][ef] = __builtin_amdgcn_mfma_f32_16x16x32_bf16(af,  bfh, acc[mf][ef], 0, 0, 0);
                    acc[mf][ef] = __builtin_amdgcn_mfma_f32_16x16x32_bf16(afl, bfh, acc[mf][ef], 0, 0, 0);
                    acc[mf][ef] = __builtin_amdgcn_mfma_f32_16x16x32_bf16(af,  bfl, acc[mf][ef], 0, 0, 0);
                }
            }
        }
    }

    // epilogue: acc -> ctxe[m][e] (fp32, pad 81) -> coalesced global [s][bh][e][m]
    __syncthreads();
#pragma unroll
    for (int mf = 0; mf < 2; ++mf)
#pragma unroll
        for (int ef = 0; ef < 5; ++ef)
#pragma unroll
            for (int r = 0; r < 4; ++r) {
                int ml = w * 32 + mf * 16 + lq * 4 + r;
                int e  = ef * 16 + lm;
                ctxe[ml * 81 + e] = acc[mf][ef][r];
            }
    __syncthreads();
    const size_t SLICE = (size_t)(B_ * HEADS_) * EPAD * M_;
    const size_t obase = (size_t)slice * SLICE + (size_t)bh * EPAD * M_;
    for (int i = t; i < EPAD * 128; i += 256) {
        int e = i >> 7, ml = i & 127;
        ctxp[obase + (size_t)e * M_ + mh * 128 + ml] = ctxe[ml * 81 + e];
    }
}

// ======================================================================
// Reduce ctx partials over slices -> bf16 hi/lo ctxT[bh][e][m]
// ======================================================================
__global__ __launch_bounds__(256) void ctx_reduce(
    const float* __restrict__ ctxp, __bf16* __restrict__ ctxTh, __bf16* __restrict__ ctxTl)
{
    int idx = blockIdx.x * 256 + threadIdx.x;     // [0, 32*80*256)
    const size_t SLICE = (size_t)(B_ * HEADS_) * EPAD * M_;
    float s = 0.f;
#pragma unroll
    for (int k = 0; k < NSPLIT; ++k) s += ctxp[(size_t)k * SLICE + idx];
    __bf16 hh = (__bf16)s;
    ctxTh[idx] = hh;
    ctxTl[idx] = (__bf16)(s - (float)hh);
}

// ======================================================================
// out via MFMA. grid (N/64, 32 bh). 4 waves, wave owns 16 n rows. No barriers.
// dash D[n16, m64-chunk] -> qf -> wave-private LDS transpose -> acc += qf@ctxT.
// Column 64 of ctxT = k_cumsum -> denominator; shfl-broadcast; bf16 hi/lo out.
// ======================================================================
__global__ __launch_bounds__(256) void out_mfma(
    const __bf16* __restrict__ Qh, const __bf16* __restrict__ Ql,
    const __bf16* __restrict__ projH, const __bf16* __restrict__ projL,
    const __bf16* __restrict__ ctxTh, const __bf16* __restrict__ ctxTl,
    __bf16* __restrict__ attnH, __bf16* __restrict__ attnL)
{
    __shared__ alignas(16) __bf16 qfh[4][16][72];
    __shared__ alignas(16) __bf16 qfl[4][16][72];

    const int t    = threadIdx.x;
    const int lane = t & 63;
    const int w    = t >> 6;
    const int lm   = lane & 15;
    const int lq   = lane >> 4;
    const int bh   = blockIdx.y;
    const int b    = bh >> 4, h = bh & 15;
    const int nw   = blockIdx.x * 64 + w * 16;    // wave's n base
    const size_t rowbase = (size_t)b * N_ * H_ + (size_t)h * DH_;

    // A dash frags (q rows), loaded once
    bf16x8 qh_[2], ql_[2];
#pragma unroll
    for (int ks = 0; ks < 2; ++ks) {
        size_t qa = rowbase + (size_t)(nw + lm) * H_ + ks * 32 + lq * 8;
        qh_[ks] = *(const bf16x8*)(Qh + qa);
        ql_[ks] = *(const bf16x8*)(Ql + qa);
    }

    const __bf16* cth = ctxTh + (size_t)bh * EPAD * M_;
    const __bf16* ctl = ctxTl + (size_t)bh * EPAD * M_;

    f32x4 accO[5];
#pragma unroll
    for (int ef = 0; ef < 5; ++ef) accO[ef] = (f32x4){0.f, 0.f, 0.f, 0.f};

    for (int mc = 0; mc < 4; ++mc) {
        const int m0 = mc * 64;
        // dash
        f32x4 dsh[4];
#pragma unroll
        for (int mf = 0; mf < 4; ++mf) {
            dsh[mf] = (f32x4){0.f, 0.f, 0.f, 0.f};
#pragma unroll
            for (int ks = 0; ks < 2; ++ks) {
                size_t pa = (size_t)(m0 + mf * 16 + lm) * 64 + ks * 32 + lq * 8;
                bf16x8 ph = *(const bf16x8*)(projH + pa);
                bf16x8 pl = *(const bf16x8*)(projL + pa);
                dsh[mf] = __builtin_amdgcn_mfma_f32_16x16x32_bf16(qh_[ks], ph, dsh[mf], 0, 0, 0);
                dsh[mf] = __builtin_amdgcn_mfma_f32_16x16x32_bf16(ql_[ks], ph, dsh[mf], 0, 0, 0);
                dsh[mf] = __builtin_amdgcn_mfma_f32_16x16x32_bf16(qh_[ks], pl, dsh[mf], 0, 0, 0);
            }
        }
        // exp -> qf bf16 hi/lo -> wave-private LDS [n16][m64]
#pragma unroll
        for (int mf = 0; mf < 4; ++mf)
#pragma unroll
            for (int r = 0; r < 4; ++r) {
                float qf = RATIO * (__expf(NORMALIZER * dsh[mf][r]) + KEPS);
                __bf16 hh = (__bf16)qf;
                int nloc = lq * 4 + r;
                qfh[w][nloc][mf * 16 + lm] = hh;
                qfl[w][nloc][mf * 16 + lm] = (__bf16)(qf - (float)hh);
            }
        // out GEMM: acc += qf[n][m] @ ctxT[e][m]
#pragma unroll
        for (int ks = 0; ks < 2; ++ks) {
            bf16x8 af  = *(const bf16x8*)&qfh[w][lm][ks * 32 + lq * 8];
            bf16x8 afl = *(const bf16x8*)&qfl[w][lm][ks * 32 + lq * 8];
#pragma unroll
            for (int ef = 0; ef < 5; ++ef) {
                size_t ca = (size_t)(ef * 16 + lm) * M_ + m0 + ks * 32 + lq * 8;
                bf16x8 bfh = *(const bf16x8*)(cth + ca);
                bf16x8 bfl = *(const bf16x8*)(ctl + ca);
                accO[ef] = __builtin_amdgcn_mfma_f32_16x16x32_bf16(af,  bfh, accO[ef], 0, 0, 0);
                accO[ef] = __builtin_amdgcn_mfma_f32_16x16x32_bf16(afl, bfh, accO[ef], 0, 0, 0);
                accO[ef] = __builtin_amdgcn_mfma_f32_16x16x32_bf16(af,  bfl, accO[ef], 0, 0, 0);
            }
        }
    }

    // denominator: ctx column 64 -> accO[4] col (64 + lm); lm==0 holds den[row]
    float dinv[4];
#pragma unroll
    for (int r = 0; r < 4; ++r) {
        float den = __shfl(accO[4][r], lane & 48);
        dinv[r] = 1.f / den;
    }
#pragma unroll
    for (int ef = 0; ef < 4; ++ef)
#pragma unroll
        for (int r = 0; r < 4; ++r) {
            float o = accO[ef][r] * dinv[r];
            __bf16 hh = (__bf16)o;
            size_t oa = rowbase + (size_t)(nw + lq * 4 + r) * H_ + ef * 16 + lm;
            attnH[oa] = hh;
            attnL[oa] = (__bf16)(o - (float)hh);
        }
}

// ======================================================================
extern "C" void kernel_launch(void* const* d_in, const int* in_sizes, int n_in,
                              void* d_out, int out_size, void* d_ws, size_t ws_size,
                              hipStream_t stream) {
    const float* hs   = (const float*)d_in[0];
    const float* Wq   = (const float*)d_in[1];
    const float* bq   = (const float*)d_in[2];
    const float* Wk   = (const float*)d_in[3];
    const float* bk   = (const float*)d_in[4];
    const float* Wv   = (const float*)d_in[5];
    const float* bv   = (const float*)d_in[6];
    const float* Wo   = (const float*)d_in[7];
    const float* bo   = (const float*)d_in[8];
    const float* proj = (const float*)d_in[9];
    float* out = (float*)d_out;

    const size_t QSZ = (size_t)B_ * N_ * H_;           // 8388608
    const size_t WSZ = (size_t)H_ * H_;                // 1048576
    const size_t CTXT = (size_t)B_ * HEADS_ * EPAD * M_;  // 655360

    __bf16* Qh  = (__bf16*)d_ws;
    __bf16* Ql  = Qh + QSZ;
    __bf16* Kh  = Ql + QSZ;
    __bf16* Kl  = Kh + QSZ;
    __bf16* Vh  = Kl + QSZ;
    __bf16* Vl  = Vh + QSZ;
    __bf16* hsH = Vl + QSZ;      // aliased as attnH after hs consumed
    __bf16* hsL = hsH + QSZ;     // aliased as attnL
    __bf16* WH  = hsL + QSZ;
    __bf16* WL  = WH + 4 * WSZ;
    __bf16* projH = WL + 4 * WSZ;
    __bf16* projL = projH + (size_t)M_ * DH_;
    __bf16* ctxTh = projL + (size_t)M_ * DH_;
    __bf16* ctxTl = ctxTh + CTXT;
    float*  diag  = (float*)(ctxTl + CTXT);
    float*  parts = diag + (size_t)B_ * HEADS_ * N_;
    float*  stab  = parts + 2048;
    float*  ctxp  = stab + 16;

    __bf16 *WqH = WH, *WkH = WH + WSZ, *WvH = WH + 2*WSZ, *WoH = WH + 3*WSZ;
    __bf16 *WqL = WL, *WkL = WL + WSZ, *WvL = WL + 2*WSZ, *WoL = WL + 3*WSZ;

    // 0) splits
    split_bf16<<<QSZ / 4 / 256, 256, 0, stream>>>(hs, hsH, hsL);
    split_w<<<dim3(WSZ / 4 / 256, 4), 256, 0, stream>>>(Wq, Wk, Wv, Wo, WH, WL);
    split_bf16<<<(M_ * DH_) / 4 / 256, 256, 0, stream>>>(proj, projH, projL);

    // 1) Q,K,V = hs @ W^T + b  -> bf16 hi/lo
    gemm_mfma3<true><<<dim3(H_ / 128, (B_ * N_) / 128, 3), 512, 0, stream>>>(
        hsH, hsL, WqH, WqL, WkH, WkL, WvH, WvL, bq, bk, bv,
        nullptr, Qh, Ql, Kh, Kl, Vh, Vl);

    // 2) diag + global stabilizer
    diag_kernel<<<2048, 256, 0, stream>>>(Kh, Kl, diag, parts);
    reduce_stab<<<1, 256, 0, stream>>>(parts, stab, 2048);

    // 3) ctx partials (MFMA)
    ctx_mfma<<<dim3(NSPLIT, 2, B_ * HEADS_), 256, 0, stream>>>(
        Kh, Kl, Vh, Vl, projH, projL, diag, stab, ctxp);

    // 4) reduce partials -> bf16 ctxT
    ctx_reduce<<<(B_ * HEADS_ * EPAD * M_) / 256, 256, 0, stream>>>(ctxp, ctxTh, ctxTl);

    // 5) out (MFMA), writes attn bf16 hi/lo (aliases hs buffers)
    out_mfma<<<dim3(N_ / 64, B_ * HEADS_), 256, 0, stream>>>(
        Qh, Ql, projH, projL, ctxTh, ctxTl, hsH, hsL);

    // 6) final projection fp32 out
    gemm_mfma3<false><<<dim3(H_ / 128, (B_ * N_) / 128, 1), 512, 0, stream>>>(
        hsH, hsL, WoH, WoL, WoH, WoL, WoH, WoL, bo, bo, bo,
        out, nullptr, nullptr, nullptr, nullptr, nullptr, nullptr);
}

// Round 4
// 494.822 us; speedup vs baseline: 1.0991x; 1.0991x over previous
//
#include <hip/hip_runtime.h>
#include <math.h>

#define B_      2
#define N_      4096
#define H_      1024
#define HEADS_  16
#define DH_     64
#define M_      256
#define NSPLIT  8
#define EPAD    80

constexpr float NORMALIZER = 0.35355339059327373f; // 64^-0.25
constexpr float RATIO      = 0.0625f;              // 256^-0.5
constexpr float KEPS       = 1e-3f;

typedef __bf16 bf16x8 __attribute__((ext_vector_type(8)));
typedef __bf16 bf16x4 __attribute__((ext_vector_type(4)));
typedef float  f32x4  __attribute__((ext_vector_type(4)));

// ======================================================================
// Split fp32 -> bf16 (hi, lo)
// ======================================================================
__global__ __launch_bounds__(256) void split_bf16(
    const float* __restrict__ src, __bf16* __restrict__ hi, __bf16* __restrict__ lo)
{
    int i = blockIdx.x * 256 + threadIdx.x;
    float4 v = ((const float4*)src)[i];
    float vv[4] = {v.x, v.y, v.z, v.w};
    bf16x4 h, l;
#pragma unroll
    for (int j = 0; j < 4; ++j) {
        __bf16 hh = (__bf16)vv[j];
        h[j] = hh;
        l[j] = (__bf16)(vv[j] - (float)hh);
    }
    ((bf16x4*)hi)[i] = h;
    ((bf16x4*)lo)[i] = l;
}

__global__ __launch_bounds__(256) void split_w(
    const float* __restrict__ W0, const float* __restrict__ W1,
    const float* __restrict__ W2, const float* __restrict__ W3,
    __bf16* __restrict__ hi, __bf16* __restrict__ lo)
{
    const float* src = W0;
    if (blockIdx.y == 1) src = W1;
    else if (blockIdx.y == 2) src = W2;
    else if (blockIdx.y == 3) src = W3;
    int i = blockIdx.x * 256 + threadIdx.x;
    size_t o = (size_t)blockIdx.y * 262144 + i;
    float4 v = ((const float4*)src)[i];
    float vv[4] = {v.x, v.y, v.z, v.w};
    bf16x4 h, l;
#pragma unroll
    for (int j = 0; j < 4; ++j) {
        __bf16 hh = (__bf16)vv[j];
        h[j] = hh;
        l[j] = (__bf16)(vv[j] - (float)hh);
    }
    ((bf16x4*)hi)[o] = h;
    ((bf16x4*)lo)[o] = l;
}

// ======================================================================
// Split-bf16 MFMA GEMM, C = A@W^T + bias. BF16OUT: write C as bf16 hi/lo.
// Round-2 verified schedule (best measured): 512 threads / 8 waves,
// wave tile 64x32, 2-phase pipelined K-loop:
//   - global_load_lds width=16 direct staging (no VGPR roundtrip)
//   - double-buffered linear LDS tiles [128][32] (64 KiB, 2 blk/CU)
//   - counted s_waitcnt vmcnt(4): next tile's 4 loads/wave stay in
//     flight across both barriers (raw s_barrier; no vmcnt(0) in loop)
//   - XOR swizzle on global source chunk + ds_read address (rule #21):
//     conflict-free (SQ_LDS_BANK_CONFLICT == 0 measured)
// NEW (T1): XCD-aware chunked blockIdx swizzle. nwg per z = 512 (%8==0,
// bijective). XCD c owns tiles {c*64..c*64+63} = 8 contiguous m-panels
// x all 8 n-panels -> A-panels fetched by ONE XCD's L2 (was all 8), W
// (4MB hi+lo) stays L2-resident. z stride 512 == 0 mod 8 keeps phase.
// ======================================================================
template<bool BF16OUT>
__global__ __launch_bounds__(512, 4) void gemm_mfma3(
    const __bf16* __restrict__ Ah, const __bf16* __restrict__ Al,
    const __bf16* __restrict__ Bh0, const __bf16* __restrict__ Bl0,
    const __bf16* __restrict__ Bh1, const __bf16* __restrict__ Bl1,
    const __bf16* __restrict__ Bh2, const __bf16* __restrict__ Bl2,
    const float* __restrict__ bi0, const float* __restrict__ bi1, const float* __restrict__ bi2,
    float* __restrict__ C0,
    __bf16* __restrict__ Ch0, __bf16* __restrict__ Cl0,
    __bf16* __restrict__ Ch1, __bf16* __restrict__ Cl1,
    __bf16* __restrict__ Ch2, __bf16* __restrict__ Cl2)
{
    const __bf16* Bh = Bh0; const __bf16* Bl = Bl0; const float* bias = bi0;
    __bf16* Ch = Ch0; __bf16* Cl = Cl0;
    if (blockIdx.z == 1) { Bh = Bh1; Bl = Bl1; bias = bi1; Ch = Ch1; Cl = Cl1; }
    else if (blockIdx.z == 2) { Bh = Bh2; Bl = Bl2; bias = bi2; Ch = Ch2; Cl = Cl2; }

    // [buf][tile][128*32] linear; tile: 0=Ah 1=Al 2=Bh 3=Bl
    __shared__ alignas(16) __bf16 lds[2][4][128 * 32];

    const int t    = threadIdx.x;
    const int lane = t & 63;
    const int lm   = lane & 15;
    const int lq   = lane >> 4;
    const int w    = t >> 6;
    const int wm   = (w >> 2) * 64;    // m half
    const int wn   = (w & 3) * 32;     // n quarter

    // T1 XCD chunked swizzle (bijective: 512 % 8 == 0)
    const int wg = blockIdx.x + 8 * blockIdx.y;   // hardware-linear within z
    const int sw = (wg & 7) * 64 + (wg >> 3);
    const int n0 = (sw & 7) * 128;
    const int m0 = (sw >> 3) * 128;
    const int K    = 1024;
    const int NK   = 32;

    // wave w stages half hw of tile tw; 4 calls x 1KiB per K-step.
    // lane -> (row = c*16 + (lane>>2), slot = lane&3); LDS dest linear.
    // Global column chunk pre-swizzled: chunk = slot ^ ((lane>>3)&3) and
    // (row>>1)&3 == (lane>>3)&3 (hw*64 and c*16 don't touch bits 1-2).
    const int tw = w >> 1;
    const int hw = w & 1;
    const __bf16* mysrc = (tw == 0) ? Ah : (tw == 1) ? Al : (tw == 2) ? Bh : Bl;
    const int     rbase = ((tw < 2) ? m0 : n0) + hw * 64;
    const int rsub   = lane >> 2;
    const int slot   = lane & 3;
    const int schunk = slot ^ ((lane >> 3) & 3);
    const __bf16* gbase = mysrc + (size_t)(rbase + rsub) * K + schunk * 8;

    f32x4 acc[4][2];
#pragma unroll
    for (int i = 0; i < 4; ++i)
#pragma unroll
        for (int j = 0; j < 2; ++j) acc[i][j] = (f32x4){0.f, 0.f, 0.f, 0.f};

    // read-side swizzle (same involution, lane-constant)
    const int swz = (lq ^ ((lm >> 1) & 3)) * 8;

    auto stage = [&](int buf, int k0) {
#pragma unroll
        for (int c = 0; c < 4; ++c) {
            const __bf16* g = gbase + (size_t)c * 16 * K + k0;
            __builtin_amdgcn_global_load_lds(
                (const __attribute__((address_space(1))) void*)g,
                (__attribute__((address_space(3))) void*)&lds[buf][tw][(hw * 64 + c * 16) * 32],
                16, 0, 0);
        }
    };

    auto compute = [&](int p) {
        const __bf16* tAh = lds[p][0];
        const __bf16* tAl = lds[p][1];
        const __bf16* tBh = lds[p][2];
        const __bf16* tBl = lds[p][3];
        bf16x8 bh[2], bl[2];
#pragma unroll
        for (int j = 0; j < 2; ++j) {
            int off = (wn + j * 16 + lm) * 32 + swz;
            bh[j] = *(const bf16x8*)&tBh[off];
            bl[j] = *(const bf16x8*)&tBl[off];
        }
#pragma unroll
        for (int i = 0; i < 4; ++i) {
            int off = (wm + i * 16 + lm) * 32 + swz;
            bf16x8 ah = *(const bf16x8*)&tAh[off];
            bf16x8 al = *(const bf16x8*)&tAl[off];
#pragma unroll
            for (int j = 0; j < 2; ++j) {
                acc[i][j] = __builtin_amdgcn_mfma_f32_16x16x32_bf16(ah, bh[j], acc[i][j], 0, 0, 0);
                acc[i][j] = __builtin_amdgcn_mfma_f32_16x16x32_bf16(al, bh[j], acc[i][j], 0, 0, 0);
                acc[i][j] = __builtin_amdgcn_mfma_f32_16x16x32_bf16(ah, bl[j], acc[i][j], 0, 0, 0);
            }
        }
    };

    stage(0, 0);
    int p = 0;
#pragma unroll 1
    for (int kk = 0; kk < NK - 1; ++kk) {
        // issue next K-step's loads (safe: prior reads of buf p^1 finished
        // before the trailing barrier of the previous iteration)
        stage(p ^ 1, (kk + 1) * 32);
        // wait only for MY oldest 4 (current buffer); next 4 stay in flight
        asm volatile("s_waitcnt vmcnt(4)" ::: "memory");
        asm volatile("s_barrier" ::: "memory");   // all waves' current tile landed
        compute(p);
        asm volatile("s_barrier" ::: "memory");   // reads done before overwrite
        p ^= 1;
    }
    asm volatile("s_waitcnt vmcnt(0)" ::: "memory");
    asm volatile("s_barrier" ::: "memory");
    compute(p);

    float bsr[2];
#pragma unroll
    for (int j = 0; j < 2; ++j) bsr[j] = bias[n0 + wn + j * 16 + lm];
#pragma unroll
    for (int i = 0; i < 4; ++i)
#pragma unroll
        for (int r = 0; r < 4; ++r) {
            int rowm = m0 + wm + i * 16 + lq * 4 + r;
#pragma unroll
            for (int j = 0; j < 2; ++j) {
                int col = n0 + wn + j * 16 + lm;
                float o = acc[i][j][r] + bsr[j];
                if (BF16OUT) {
                    __bf16 hh = (__bf16)o;
                    Ch[(size_t)rowm * 1024 + col] = hh;
                    Cl[(size_t)rowm * 1024 + col] = (__bf16)(o - (float)hh);
                } else {
                    C0[(size_t)rowm * 1024 + col] = o;
                }
            }
        }
}

// ======================================================================
// diag_k from bf16 hi/lo K
// ======================================================================
__global__ __launch_bounds__(256) void diag_kernel(
    const __bf16* __restrict__ Kh, const __bf16* __restrict__ Kl,
    float* __restrict__ diag, float* __restrict__ partials)
{
    int gt = blockIdx.x * 256 + threadIdx.x;
    int r  = gt >> 2;
    int q  = gt & 3;
    const bf16x8* ph = (const bf16x8*)(Kh + (size_t)r * 64 + q * 16);
    const bf16x8* pl = (const bf16x8*)(Kl + (size_t)r * 64 + q * 16);
    float s = 0.f;
#pragma unroll
    for (int i = 0; i < 2; ++i) {
        bf16x8 vh = ph[i], vl = pl[i];
#pragma unroll
        for (int j = 0; j < 8; ++j) {
            float x = (float)vh[j] + (float)vl[j];
            s += x * x;
        }
    }
    s += __shfl_xor(s, 1);
    s += __shfl_xor(s, 2);
    float d = -0.5f * s;
    if (q == 0) {
        int h = r & 15, bn = r >> 4;
        int n = bn & 4095, b = bn >> 12;
        diag[(((size_t)b * 16 + h) << 12) + n] = d;
    }
    __shared__ float red[256];
    red[threadIdx.x] = d;
    __syncthreads();
    for (int s2 = 128; s2 > 0; s2 >>= 1) {
        if (threadIdx.x < s2) red[threadIdx.x] = fmaxf(red[threadIdx.x], red[threadIdx.x + s2]);
        __syncthreads();
    }
    if (threadIdx.x == 0) partials[blockIdx.x] = red[0];
}

__global__ __launch_bounds__(256) void reduce_stab(
    const float* __restrict__ partials, float* __restrict__ stab, int n)
{
    float m = -3.0e38f;
    for (int i = threadIdx.x; i < n; i += 256) m = fmaxf(m, partials[i]);
    __shared__ float red[256];
    red[threadIdx.x] = m;
    __syncthreads();
    for (int s2 = 128; s2 > 0; s2 >>= 1) {
        if (threadIdx.x < s2) red[threadIdx.x] = fmaxf(red[threadIdx.x], red[threadIdx.x + s2]);
        __syncthreads();
    }
    if (threadIdx.x == 0) stab[0] = red[0];
}

// ======================================================================
// ctx via MFMA. grid (NSPLIT, 2 m-halves, 32 bh). 4 waves, wave owns 32 m.
// dash: D[n64, m32/wave] = K@proj^T (3 split products, operands from global)
// exp -> kf bf16 hi/lo -> LDS transpose kfT[m][n] -> ctx += kfT @ vT[e][n]
// e=64 is ones (k_cumsum); e 65..79 zero pad. fp32 partials out [s][bh][e][m].
// kfT transpose stores vectorized: r indexes consecutive n columns ->
// one bf16x4 (b64) write replaces 4 scalar b16 writes (4x fewer LDS ops
// in the serial chain; 4-way bank aliasing ~1.6x per m136, net win).
// ======================================================================
__global__ __launch_bounds__(256) void ctx_mfma(
    const __bf16* __restrict__ Kh, const __bf16* __restrict__ Kl,
    const __bf16* __restrict__ Vh, const __bf16* __restrict__ Vl,
    const __bf16* __restrict__ projH, const __bf16* __restrict__ projL,
    const float* __restrict__ diag, const float* __restrict__ stabp,
    float* __restrict__ ctxp)
{
    __shared__ alignas(16) char ldsbuf[59904];
    __shared__ float dg[64];
    __bf16* kfTh = (__bf16*)ldsbuf;              // [128][72]
    __bf16* kfTl = kfTh + 9216;                  // [128][72]
    __bf16* vTh  = kfTl + 9216;                  // [80][72]
    __bf16* vTl  = vTh + 5760;                   // [80][72]
    float*  ctxe = (float*)ldsbuf;               // [128][81] (epilogue alias)

    const int t    = threadIdx.x;
    const int lane = t & 63;
    const int w    = t >> 6;
    const int lm   = lane & 15;
    const int lq   = lane >> 4;
    const int bh   = blockIdx.z;
    const int b    = bh >> 4, h = bh & 15;
    const int mh   = blockIdx.y;
    const int slice = blockIdx.x;
    const int mwave = mh * 128 + w * 32;          // global m base for wave
    const float stab = stabp[0];
    const size_t rowbase = (size_t)b * N_ * H_ + (size_t)h * DH_;
    const float* diag_bh = diag + (size_t)bh * N_;

    // vT constant rows: e=64 -> ones (hi), e>64 -> zero
    for (int idx = t; idx < 16 * 72; idx += 256) {
        int e = 64 + idx / 72, n = idx % 72;
        vTh[e * 72 + n] = (e == 64 && n < 64) ? (__bf16)1.0f : (__bf16)0.0f;
        vTl[e * 72 + n] = (__bf16)0.0f;
    }

    // proj B-frags, register-cached for whole kernel: [mf][ks]
    bf16x8 ph[2][2], pl[2][2];
#pragma unroll
    for (int mf = 0; mf < 2; ++mf)
#pragma unroll
        for (int ks = 0; ks < 2; ++ks) {
            size_t pa = (size_t)(mwave + mf * 16 + lm) * 64 + ks * 32 + lq * 8;
            ph[mf][ks] = *(const bf16x8*)(projH + pa);
            pl[mf][ks] = *(const bf16x8*)(projL + pa);
        }

    f32x4 acc[2][5];
#pragma unroll
    for (int mf = 0; mf < 2; ++mf)
#pragma unroll
        for (int ef = 0; ef < 5; ++ef) acc[mf][ef] = (f32x4){0.f, 0.f, 0.f, 0.f};

    for (int tile = 0; tile < 8; ++tile) {
        const int n0 = slice * (N_ / NSPLIT) + tile * 64;
        __syncthreads();   // barrier A: prior GEMM reads of vT done

        // stage vT rows 0..63 (transpose V[n][d] -> vT[d][n])
        {
            int nl = t >> 2, dc = (t & 3) * 16;
            size_t va = rowbase + (size_t)(n0 + nl) * H_ + dc;
            bf16x8 v0 = *(const bf16x8*)(Vh + va);
            bf16x8 v1 = *(const bf16x8*)(Vh + va + 8);
            bf16x8 u0 = *(const bf16x8*)(Vl + va);
            bf16x8 u1 = *(const bf16x8*)(Vl + va + 8);
#pragma unroll
            for (int j = 0; j < 8; ++j) {
                vTh[(dc + j) * 72 + nl]     = v0[j];
                vTh[(dc + 8 + j) * 72 + nl] = v1[j];
                vTl[(dc + j) * 72 + nl]     = u0[j];
                vTl[(dc + 8 + j) * 72 + nl] = u1[j];
            }
        }
        if (t < 64) dg[t] = diag_bh[n0 + t] - stab;

        // dash MFMA (global operands, no LDS dependency)
        f32x4 dsh[4][2];
#pragma unroll
        for (int nf = 0; nf < 4; ++nf) {
#pragma unroll
            for (int mf = 0; mf < 2; ++mf) dsh[nf][mf] = (f32x4){0.f, 0.f, 0.f, 0.f};
            bf16x8 ah[2], al[2];
#pragma unroll
            for (int ks = 0; ks < 2; ++ks) {
                size_t ka = rowbase + (size_t)(n0 + nf * 16 + lm) * H_ + ks * 32 + lq * 8;
                ah[ks] = *(const bf16x8*)(Kh + ka);
                al[ks] = *(const bf16x8*)(Kl + ka);
            }
#pragma unroll
            for (int mf = 0; mf < 2; ++mf)
#pragma unroll
                for (int ks = 0; ks < 2; ++ks) {
                    dsh[nf][mf] = __builtin_amdgcn_mfma_f32_16x16x32_bf16(ah[ks], ph[mf][ks], dsh[nf][mf], 0, 0, 0);
                    dsh[nf][mf] = __builtin_amdgcn_mfma_f32_16x16x32_bf16(al[ks], ph[mf][ks], dsh[nf][mf], 0, 0, 0);
                    dsh[nf][mf] = __builtin_amdgcn_mfma_f32_16x16x32_bf16(ah[ks], pl[mf][ks], dsh[nf][mf], 0, 0, 0);
                }
        }

        __syncthreads();   // barrier B: vT + dg staged

        // exp -> kf bf16 hi/lo -> kfT (wave-private rows), b64 writes
#pragma unroll
        for (int nf = 0; nf < 4; ++nf) {
            float4 dgv = *(const float4*)&dg[nf * 16 + lq * 4];
            float dga[4] = {dgv.x, dgv.y, dgv.z, dgv.w};
#pragma unroll
            for (int mf = 0; mf < 2; ++mf) {
                int mrow = w * 32 + mf * 16 + lm;   // block-local m row
                bf16x4 vh_, vl_;
#pragma unroll
                for (int r = 0; r < 4; ++r) {
                    float kf = RATIO * (__expf(dga[r] + NORMALIZER * dsh[nf][mf][r]) + KEPS);
                    __bf16 hh = (__bf16)kf;
                    vh_[r] = hh;
                    vl_[r] = (__bf16)(kf - (float)hh);
                }
                int nbase = nf * 16 + lq * 4;       // multiple of 4 -> 8B aligned
                *(bf16x4*)&kfTh[mrow * 72 + nbase] = vh_;
                *(bf16x4*)&kfTl[mrow * 72 + nbase] = vl_;
            }
        }

        // ctx accumulate: acc[mf][ef] += kfT[m][n] @ vT[e][n]
#pragma unroll
        for (int ks = 0; ks < 2; ++ks) {
#pragma unroll
            for (int mf = 0; mf < 2; ++mf) {
                bf16x8 af = *(const bf16x8*)&kfTh[(w * 32 + mf * 16 + lm) * 72 + ks * 32 + lq * 8];
                bf16x8 afl = *(const bf16x8*)&kfTl[(w * 32 + mf * 16 + lm) * 72 + ks * 32 + lq * 8];
#pragma unroll
                for (int ef = 0; ef < 5; ++ef) {
                    bf16x8 bfh = *(const bf16x8*)&vTh[(ef * 16 + lm) * 72 + ks * 32 + lq * 8];
                    bf16x8 bfl = *(const bf16x8*)&vTl[(ef * 16 + lm) * 72 + ks * 32 + lq * 8];
                    acc[mf][ef] = __builtin_amdgcn_mfma_f32_16x16x32_bf16(af,  bfh, acc[mf][ef], 0, 0, 0);
                    acc[mf][ef] = __builtin_amdgcn_mfma_f32_16x16x32_bf16(afl, bfh, acc[mf][ef], 0, 0, 0);
                    acc[mf][ef] = __builtin_amdgcn_mfma_f32_16x16x32_bf16(af,  bfl, acc[mf][ef], 0, 0, 0);
                }
            }
        }
    }

    // epilogue: acc -> ctxe[m][e] (fp32, pad 81) -> coalesced global [s][bh][e][m]
    __syncthreads();
#pragma unroll
    for (int mf = 0; mf < 2; ++mf)
#pragma unroll
        for (int ef = 0; ef < 5; ++ef)
#pragma unroll
            for (int r = 0; r < 4; ++r) {
                int ml = w * 32 + mf * 16 + lq * 4 + r;
                int e  = ef * 16 + lm;
                ctxe[ml * 81 + e] = acc[mf][ef][r];
            }
    __syncthreads();
    const size_t SLICE = (size_t)(B_ * HEADS_) * EPAD * M_;
    const size_t obase = (size_t)slice * SLICE + (size_t)bh * EPAD * M_;
    for (int i = t; i < EPAD * 128; i += 256) {
        int e = i >> 7, ml = i & 127;
        ctxp[obase + (size_t)e * M_ + mh * 128 + ml] = ctxe[ml * 81 + e];
    }
}

// ======================================================================
// Reduce ctx partials over slices -> bf16 hi/lo ctxT[bh][e][m]
// ======================================================================
__global__ __launch_bounds__(256) void ctx_reduce(
    const float* __restrict__ ctxp, __bf16* __restrict__ ctxTh, __bf16* __restrict__ ctxTl)
{
    int idx = blockIdx.x * 256 + threadIdx.x;     // [0, 32*80*256)
    const size_t SLICE = (size_t)(B_ * HEADS_) * EPAD * M_;
    float s = 0.f;
#pragma unroll
    for (int k = 0; k < NSPLIT; ++k) s += ctxp[(size_t)k * SLICE + idx];
    __bf16 hh = (__bf16)s;
    ctxTh[idx] = hh;
    ctxTl[idx] = (__bf16)(s - (float)hh);
}

// ======================================================================
// out via MFMA. grid (N/64, 32 bh). 4 waves, wave owns 16 n rows. No barriers.
// dash D[n16, m64-chunk] -> qf -> wave-private LDS transpose -> acc += qf@ctxT.
// Column 64 of ctxT = k_cumsum -> denominator; shfl-broadcast; bf16 hi/lo out.
// ======================================================================
__global__ __launch_bounds__(256) void out_mfma(
    const __bf16* __restrict__ Qh, const __bf16* __restrict__ Ql,
    const __bf16* __restrict__ projH, const __bf16* __restrict__ projL,
    const __bf16* __restrict__ ctxTh, const __bf16* __restrict__ ctxTl,
    __bf16* __restrict__ attnH, __bf16* __restrict__ attnL)
{
    __shared__ alignas(16) __bf16 qfh[4][16][72];
    __shared__ alignas(16) __bf16 qfl[4][16][72];

    const int t    = threadIdx.x;
    const int lane = t & 63;
    const int w    = t >> 6;
    const int lm   = lane & 15;
    const int lq   = lane >> 4;
    const int bh   = blockIdx.y;
    const int b    = bh >> 4, h = bh & 15;
    const int nw   = blockIdx.x * 64 + w * 16;    // wave's n base
    const size_t rowbase = (size_t)b * N_ * H_ + (size_t)h * DH_;

    // A dash frags (q rows), loaded once
    bf16x8 qh_[2], ql_[2];
#pragma unroll
    for (int ks = 0; ks < 2; ++ks) {
        size_t qa = rowbase + (size_t)(nw + lm) * H_ + ks * 32 + lq * 8;
        qh_[ks] = *(const bf16x8*)(Qh + qa);
        ql_[ks] = *(const bf16x8*)(Ql + qa);
    }

    const __bf16* cth = ctxTh + (size_t)bh * EPAD * M_;
    const __bf16* ctl = ctxTl + (size_t)bh * EPAD * M_;

    f32x4 accO[5];
#pragma unroll
    for (int ef = 0; ef < 5; ++ef) accO[ef] = (f32x4){0.f, 0.f, 0.f, 0.f};

    for (int mc = 0; mc < 4; ++mc) {
        const int m0 = mc * 64;
        // dash
        f32x4 dsh[4];
#pragma unroll
        for (int mf = 0; mf < 4; ++mf) {
            dsh[mf] = (f32x4){0.f, 0.f, 0.f, 0.f};
#pragma unroll
            for (int ks = 0; ks < 2; ++ks) {
                size_t pa = (size_t)(m0 + mf * 16 + lm) * 64 + ks * 32 + lq * 8;
                bf16x8 ph = *(const bf16x8*)(projH + pa);
                bf16x8 pl = *(const bf16x8*)(projL + pa);
                dsh[mf] = __builtin_amdgcn_mfma_f32_16x16x32_bf16(qh_[ks], ph, dsh[mf], 0, 0, 0);
                dsh[mf] = __builtin_amdgcn_mfma_f32_16x16x32_bf16(ql_[ks], ph, dsh[mf], 0, 0, 0);
                dsh[mf] = __builtin_amdgcn_mfma_f32_16x16x32_bf16(qh_[ks], pl, dsh[mf], 0, 0, 0);
            }
        }
        // exp -> qf bf16 hi/lo -> wave-private LDS [n16][m64]
#pragma unroll
        for (int mf = 0; mf < 4; ++mf)
#pragma unroll
            for (int r = 0; r < 4; ++r) {
                float qf = RATIO * (__expf(NORMALIZER * dsh[mf][r]) + KEPS);
                __bf16 hh = (__bf16)qf;
                int nloc = lq * 4 + r;
                qfh[w][nloc][mf * 16 + lm] = hh;
                qfl[w][nloc][mf * 16 + lm] = (__bf16)(qf - (float)hh);
            }
        // out GEMM: acc += qf[n][m] @ ctxT[e][m]
#pragma unroll
        for (int ks = 0; ks < 2; ++ks) {
            bf16x8 af  = *(const bf16x8*)&qfh[w][lm][ks * 32 + lq * 8];
            bf16x8 afl = *(const bf16x8*)&qfl[w][lm][ks * 32 + lq * 8];
#pragma unroll
            for (int ef = 0; ef < 5; ++ef) {
                size_t ca = (size_t)(ef * 16 + lm) * M_ + m0 + ks * 32 + lq * 8;
                bf16x8 bfh = *(const bf16x8*)(cth + ca);
                bf16x8 bfl = *(const bf16x8*)(ctl + ca);
                accO[ef] = __builtin_amdgcn_mfma_f32_16x16x32_bf16(af,  bfh, accO[ef], 0, 0, 0);
                accO[ef] = __builtin_amdgcn_mfma_f32_16x16x32_bf16(afl, bfh, accO[ef], 0, 0, 0);
                accO[ef] = __builtin_amdgcn_mfma_f32_16x16x32_bf16(af,  bfl, accO[ef], 0, 0, 0);
            }
        }
    }

    // denominator: ctx column 64 -> accO[4] col (64 + lm); lm==0 holds den[row]
    float dinv[4];
#pragma unroll
    for (int r = 0; r < 4; ++r) {
        float den = __shfl(accO[4][r], lane & 48);
        dinv[r] = 1.f / den;
    }
#pragma unroll
    for (int ef = 0; ef < 4; ++ef)
#pragma unroll
        for (int r = 0; r < 4; ++r) {
            float o = accO[ef][r] * dinv[r];
            __bf16 hh = (__bf16)o;
            size_t oa = rowbase + (size_t)(nw + lq * 4 + r) * H_ + ef * 16 + lm;
            attnH[oa] = hh;
            attnL[oa] = (__bf16)(o - (float)hh);
        }
}

// ======================================================================
extern "C" void kernel_launch(void* const* d_in, const int* in_sizes, int n_in,
                              void* d_out, int out_size, void* d_ws, size_t ws_size,
                              hipStream_t stream) {
    const float* hs   = (const float*)d_in[0];
    const float* Wq   = (const float*)d_in[1];
    const float* bq   = (const float*)d_in[2];
    const float* Wk   = (const float*)d_in[3];
    const float* bk   = (const float*)d_in[4];
    const float* Wv   = (const float*)d_in[5];
    const float* bv   = (const float*)d_in[6];
    const float* Wo   = (const float*)d_in[7];
    const float* bo   = (const float*)d_in[8];
    const float* proj = (const float*)d_in[9];
    float* out = (float*)d_out;

    const size_t QSZ = (size_t)B_ * N_ * H_;           // 8388608
    const size_t WSZ = (size_t)H_ * H_;                // 1048576
    const size_t CTXT = (size_t)B_ * HEADS_ * EPAD * M_;  // 655360

    __bf16* Qh  = (__bf16*)d_ws;
    __bf16* Ql  = Qh + QSZ;
    __bf16* Kh  = Ql + QSZ;
    __bf16* Kl  = Kh + QSZ;
    __bf16* Vh  = Kl + QSZ;
    __bf16* Vl  = Vh + QSZ;
    __bf16* hsH = Vl + QSZ;      // aliased as attnH after hs consumed
    __bf16* hsL = hsH + QSZ;     // aliased as attnL
    __bf16* WH  = hsL + QSZ;
    __bf16* WL  = WH + 4 * WSZ;
    __bf16* projH = WL + 4 * WSZ;
    __bf16* projL = projH + (size_t)M_ * DH_;
    __bf16* ctxTh = projL + (size_t)M_ * DH_;
    __bf16* ctxTl = ctxTh + CTXT;
    float*  diag  = (float*)(ctxTl + CTXT);
    float*  parts = diag + (size_t)B_ * HEADS_ * N_;
    float*  stab  = parts + 2048;
    float*  ctxp  = stab + 16;

    __bf16 *WqH = WH, *WkH = WH + WSZ, *WvH = WH + 2*WSZ, *WoH = WH + 3*WSZ;
    __bf16 *WqL = WL, *WkL = WL + WSZ, *WvL = WL + 2*WSZ, *WoL = WL + 3*WSZ;

    // 0) splits
    split_bf16<<<QSZ / 4 / 256, 256, 0, stream>>>(hs, hsH, hsL);
    split_w<<<dim3(WSZ / 4 / 256, 4), 256, 0, stream>>>(Wq, Wk, Wv, Wo, WH, WL);
    split_bf16<<<(M_ * DH_) / 4 / 256, 256, 0, stream>>>(proj, projH, projL);

    // 1) Q,K,V = hs @ W^T + b  -> bf16 hi/lo
    gemm_mfma3<true><<<dim3(H_ / 128, (B_ * N_) / 128, 3), 512, 0, stream>>>(
        hsH, hsL, WqH, WqL, WkH, WkL, WvH, WvL, bq, bk, bv,
        nullptr, Qh, Ql, Kh, Kl, Vh, Vl);

    // 2) diag + global stabilizer
    diag_kernel<<<2048, 256, 0, stream>>>(Kh, Kl, diag, parts);
    reduce_stab<<<1, 256, 0, stream>>>(parts, stab, 2048);

    // 3) ctx partials (MFMA)
    ctx_mfma<<<dim3(NSPLIT, 2, B_ * HEADS_), 256, 0, stream>>>(
        Kh, Kl, Vh, Vl, projH, projL, diag, stab, ctxp);

    // 4) reduce partials -> bf16 ctxT
    ctx_reduce<<<(B_ * HEADS_ * EPAD * M_) / 256, 256, 0, stream>>>(ctxp, ctxTh, ctxTl);

    // 5) out (MFMA), writes attn bf16 hi/lo (aliases hs buffers)
    out_mfma<<<dim3(N_ / 64, B_ * HEADS_), 256, 0, stream>>>(
        Qh, Ql, projH, projL, ctxTh, ctxTl, hsH, hsL);

    // 6) final projection fp32 out
    gemm_mfma3<false><<<dim3(H_ / 128, (B_ * N_) / 128, 1), 512, 0, stream>>>(
        hsH, hsL, WoH, WoL, WoH, WoL, WoH, WoL, bo, bo, bo,
        out, nullptr, nullptr, nullptr, nullptr, nullptr, nullptr);
}

// Round 5
// 451.493 us; speedup vs baseline: 1.2046x; 1.0960x over previous
//
#include <hip/hip_runtime.h>
#include <math.h>

#define B_      2
#define N_      4096
#define H_      1024
#define HEADS_  16
#define DH_     64
#define M_      256
#define NSPLIT  8
#define EPAD    80

constexpr float NORMALIZER = 0.35355339059327373f; // 64^-0.25
constexpr float RATIO      = 0.0625f;              // 256^-0.5
constexpr float KEPS       = 1e-3f;

typedef __bf16 bf16x8 __attribute__((ext_vector_type(8)));
typedef __bf16 bf16x4 __attribute__((ext_vector_type(4)));
typedef float  f32x4  __attribute__((ext_vector_type(4)));

// ======================================================================
// Split fp32 -> bf16 (hi, lo)
// ======================================================================
__global__ __launch_bounds__(256) void split_bf16(
    const float* __restrict__ src, __bf16* __restrict__ hi, __bf16* __restrict__ lo)
{
    int i = blockIdx.x * 256 + threadIdx.x;
    float4 v = ((const float4*)src)[i];
    float vv[4] = {v.x, v.y, v.z, v.w};
    bf16x4 h, l;
#pragma unroll
    for (int j = 0; j < 4; ++j) {
        __bf16 hh = (__bf16)vv[j];
        h[j] = hh;
        l[j] = (__bf16)(vv[j] - (float)hh);
    }
    ((bf16x4*)hi)[i] = h;
    ((bf16x4*)lo)[i] = l;
}

__global__ __launch_bounds__(256) void split_w(
    const float* __restrict__ W0, const float* __restrict__ W1,
    const float* __restrict__ W2, const float* __restrict__ W3,
    __bf16* __restrict__ hi, __bf16* __restrict__ lo)
{
    const float* src = W0;
    if (blockIdx.y == 1) src = W1;
    else if (blockIdx.y == 2) src = W2;
    else if (blockIdx.y == 3) src = W3;
    int i = blockIdx.x * 256 + threadIdx.x;
    size_t o = (size_t)blockIdx.y * 262144 + i;
    float4 v = ((const float4*)src)[i];
    float vv[4] = {v.x, v.y, v.z, v.w};
    bf16x4 h, l;
#pragma unroll
    for (int j = 0; j < 4; ++j) {
        __bf16 hh = (__bf16)vv[j];
        h[j] = hh;
        l[j] = (__bf16)(vv[j] - (float)hh);
    }
    ((bf16x4*)hi)[o] = h;
    ((bf16x4*)lo)[o] = l;
}

// ======================================================================
// Split-bf16 MFMA GEMM, C = A@W^T + bias. BF16OUT: write C as bf16 hi/lo.
// Round-2 verified schedule + T1 XCD chunked swizzle (round-4 verified:
// FETCH 407->139 MB, MfmaUtil 49%).
// ======================================================================
template<bool BF16OUT>
__global__ __launch_bounds__(512, 4) void gemm_mfma3(
    const __bf16* __restrict__ Ah, const __bf16* __restrict__ Al,
    const __bf16* __restrict__ Bh0, const __bf16* __restrict__ Bl0,
    const __bf16* __restrict__ Bh1, const __bf16* __restrict__ Bl1,
    const __bf16* __restrict__ Bh2, const __bf16* __restrict__ Bl2,
    const float* __restrict__ bi0, const float* __restrict__ bi1, const float* __restrict__ bi2,
    float* __restrict__ C0,
    __bf16* __restrict__ Ch0, __bf16* __restrict__ Cl0,
    __bf16* __restrict__ Ch1, __bf16* __restrict__ Cl1,
    __bf16* __restrict__ Ch2, __bf16* __restrict__ Cl2)
{
    const __bf16* Bh = Bh0; const __bf16* Bl = Bl0; const float* bias = bi0;
    __bf16* Ch = Ch0; __bf16* Cl = Cl0;
    if (blockIdx.z == 1) { Bh = Bh1; Bl = Bl1; bias = bi1; Ch = Ch1; Cl = Cl1; }
    else if (blockIdx.z == 2) { Bh = Bh2; Bl = Bl2; bias = bi2; Ch = Ch2; Cl = Cl2; }

    // [buf][tile][128*32] linear; tile: 0=Ah 1=Al 2=Bh 3=Bl
    __shared__ alignas(16) __bf16 lds[2][4][128 * 32];

    const int t    = threadIdx.x;
    const int lane = t & 63;
    const int lm   = lane & 15;
    const int lq   = lane >> 4;
    const int w    = t >> 6;
    const int wm   = (w >> 2) * 64;    // m half
    const int wn   = (w & 3) * 32;     // n quarter

    // T1 XCD chunked swizzle (bijective: 512 % 8 == 0)
    const int wg = blockIdx.x + 8 * blockIdx.y;   // hardware-linear within z
    const int sw = (wg & 7) * 64 + (wg >> 3);
    const int n0 = (sw & 7) * 128;
    const int m0 = (sw >> 3) * 128;
    const int K    = 1024;
    const int NK   = 32;

    const int tw = w >> 1;
    const int hw = w & 1;
    const __bf16* mysrc = (tw == 0) ? Ah : (tw == 1) ? Al : (tw == 2) ? Bh : Bl;
    const int     rbase = ((tw < 2) ? m0 : n0) + hw * 64;
    const int rsub   = lane >> 2;
    const int slot   = lane & 3;
    const int schunk = slot ^ ((lane >> 3) & 3);
    const __bf16* gbase = mysrc + (size_t)(rbase + rsub) * K + schunk * 8;

    f32x4 acc[4][2];
#pragma unroll
    for (int i = 0; i < 4; ++i)
#pragma unroll
        for (int j = 0; j < 2; ++j) acc[i][j] = (f32x4){0.f, 0.f, 0.f, 0.f};

    // read-side swizzle (same involution, lane-constant)
    const int swz = (lq ^ ((lm >> 1) & 3)) * 8;

    auto stage = [&](int buf, int k0) {
#pragma unroll
        for (int c = 0; c < 4; ++c) {
            const __bf16* g = gbase + (size_t)c * 16 * K + k0;
            __builtin_amdgcn_global_load_lds(
                (const __attribute__((address_space(1))) void*)g,
                (__attribute__((address_space(3))) void*)&lds[buf][tw][(hw * 64 + c * 16) * 32],
                16, 0, 0);
        }
    };

    auto compute = [&](int p) {
        const __bf16* tAh = lds[p][0];
        const __bf16* tAl = lds[p][1];
        const __bf16* tBh = lds[p][2];
        const __bf16* tBl = lds[p][3];
        bf16x8 bh[2], bl[2];
#pragma unroll
        for (int j = 0; j < 2; ++j) {
            int off = (wn + j * 16 + lm) * 32 + swz;
            bh[j] = *(const bf16x8*)&tBh[off];
            bl[j] = *(const bf16x8*)&tBl[off];
        }
#pragma unroll
        for (int i = 0; i < 4; ++i) {
            int off = (wm + i * 16 + lm) * 32 + swz;
            bf16x8 ah = *(const bf16x8*)&tAh[off];
            bf16x8 al = *(const bf16x8*)&tAl[off];
#pragma unroll
            for (int j = 0; j < 2; ++j) {
                acc[i][j] = __builtin_amdgcn_mfma_f32_16x16x32_bf16(ah, bh[j], acc[i][j], 0, 0, 0);
                acc[i][j] = __builtin_amdgcn_mfma_f32_16x16x32_bf16(al, bh[j], acc[i][j], 0, 0, 0);
                acc[i][j] = __builtin_amdgcn_mfma_f32_16x16x32_bf16(ah, bl[j], acc[i][j], 0, 0, 0);
            }
        }
    };

    stage(0, 0);
    int p = 0;
#pragma unroll 1
    for (int kk = 0; kk < NK - 1; ++kk) {
        stage(p ^ 1, (kk + 1) * 32);
        asm volatile("s_waitcnt vmcnt(4)" ::: "memory");
        asm volatile("s_barrier" ::: "memory");
        compute(p);
        asm volatile("s_barrier" ::: "memory");
        p ^= 1;
    }
    asm volatile("s_waitcnt vmcnt(0)" ::: "memory");
    asm volatile("s_barrier" ::: "memory");
    compute(p);

    float bsr[2];
#pragma unroll
    for (int j = 0; j < 2; ++j) bsr[j] = bias[n0 + wn + j * 16 + lm];
#pragma unroll
    for (int i = 0; i < 4; ++i)
#pragma unroll
        for (int r = 0; r < 4; ++r) {
            int rowm = m0 + wm + i * 16 + lq * 4 + r;
#pragma unroll
            for (int j = 0; j < 2; ++j) {
                int col = n0 + wn + j * 16 + lm;
                float o = acc[i][j][r] + bsr[j];
                if (BF16OUT) {
                    __bf16 hh = (__bf16)o;
                    Ch[(size_t)rowm * 1024 + col] = hh;
                    Cl[(size_t)rowm * 1024 + col] = (__bf16)(o - (float)hh);
                } else {
                    C0[(size_t)rowm * 1024 + col] = o;
                }
            }
        }
}

// ======================================================================
// diag_k from bf16 hi/lo K
// ======================================================================
__global__ __launch_bounds__(256) void diag_kernel(
    const __bf16* __restrict__ Kh, const __bf16* __restrict__ Kl,
    float* __restrict__ diag, float* __restrict__ partials)
{
    int gt = blockIdx.x * 256 + threadIdx.x;
    int r  = gt >> 2;
    int q  = gt & 3;
    const bf16x8* ph = (const bf16x8*)(Kh + (size_t)r * 64 + q * 16);
    const bf16x8* pl = (const bf16x8*)(Kl + (size_t)r * 64 + q * 16);
    float s = 0.f;
#pragma unroll
    for (int i = 0; i < 2; ++i) {
        bf16x8 vh = ph[i], vl = pl[i];
#pragma unroll
        for (int j = 0; j < 8; ++j) {
            float x = (float)vh[j] + (float)vl[j];
            s += x * x;
        }
    }
    s += __shfl_xor(s, 1);
    s += __shfl_xor(s, 2);
    float d = -0.5f * s;
    if (q == 0) {
        int h = r & 15, bn = r >> 4;
        int n = bn & 4095, b = bn >> 12;
        diag[(((size_t)b * 16 + h) << 12) + n] = d;
    }
    __shared__ float red[256];
    red[threadIdx.x] = d;
    __syncthreads();
    for (int s2 = 128; s2 > 0; s2 >>= 1) {
        if (threadIdx.x < s2) red[threadIdx.x] = fmaxf(red[threadIdx.x], red[threadIdx.x + s2]);
        __syncthreads();
    }
    if (threadIdx.x == 0) partials[blockIdx.x] = red[0];
}

__global__ __launch_bounds__(256) void reduce_stab(
    const float* __restrict__ partials, float* __restrict__ stab, int n)
{
    float m = -3.0e38f;
    for (int i = threadIdx.x; i < n; i += 256) m = fmaxf(m, partials[i]);
    __shared__ float red[256];
    red[threadIdx.x] = m;
    __syncthreads();
    for (int s2 = 128; s2 > 0; s2 >>= 1) {
        if (threadIdx.x < s2) red[threadIdx.x] = fmaxf(red[threadIdx.x], red[threadIdx.x + s2]);
        __syncthreads();
    }
    if (threadIdx.x == 0) stab[0] = red[0];
}

// ======================================================================
// ctx via MFMA. grid (NSPLIT, 2 m-halves, 32 bh). 4 waves, wave owns 32 m.
// T14 async-STAGE split: next tile's V global loads issue right after
// barrier B (hidden under exp + ctx-GEMM); LDS writes happen after the
// next barrier A from registers -> V-load latency off the serial chain.
// ======================================================================
__global__ __launch_bounds__(256) void ctx_mfma(
    const __bf16* __restrict__ Kh, const __bf16* __restrict__ Kl,
    const __bf16* __restrict__ Vh, const __bf16* __restrict__ Vl,
    const __bf16* __restrict__ projH, const __bf16* __restrict__ projL,
    const float* __restrict__ diag, const float* __restrict__ stabp,
    float* __restrict__ ctxp)
{
    __shared__ alignas(16) char ldsbuf[59904];
    __shared__ float dg[64];
    __bf16* kfTh = (__bf16*)ldsbuf;              // [128][72]
    __bf16* kfTl = kfTh + 9216;                  // [128][72]
    __bf16* vTh  = kfTl + 9216;                  // [80][72]
    __bf16* vTl  = vTh + 5760;                   // [80][72]
    float*  ctxe = (float*)ldsbuf;               // [128][81] (epilogue alias)

    const int t    = threadIdx.x;
    const int lane = t & 63;
    const int w    = t >> 6;
    const int lm   = lane & 15;
    const int lq   = lane >> 4;
    const int bh   = blockIdx.z;
    const int b    = bh >> 4, h = bh & 15;
    const int mh   = blockIdx.y;
    const int slice = blockIdx.x;
    const int mwave = mh * 128 + w * 32;          // global m base for wave
    const float stab = stabp[0];
    const size_t rowbase = (size_t)b * N_ * H_ + (size_t)h * DH_;
    const float* diag_bh = diag + (size_t)bh * N_;

    // vT constant rows: e=64 -> ones (hi), e>64 -> zero
    for (int idx = t; idx < 16 * 72; idx += 256) {
        int e = 64 + idx / 72, n = idx % 72;
        vTh[e * 72 + n] = (e == 64 && n < 64) ? (__bf16)1.0f : (__bf16)0.0f;
        vTl[e * 72 + n] = (__bf16)0.0f;
    }

    // proj B-frags, register-cached for whole kernel: [mf][ks]
    bf16x8 ph[2][2], pl[2][2];
#pragma unroll
    for (int mf = 0; mf < 2; ++mf)
#pragma unroll
        for (int ks = 0; ks < 2; ++ks) {
            size_t pa = (size_t)(mwave + mf * 16 + lm) * 64 + ks * 32 + lq * 8;
            ph[mf][ks] = *(const bf16x8*)(projH + pa);
            pl[mf][ks] = *(const bf16x8*)(projL + pa);
        }

    f32x4 acc[2][5];
#pragma unroll
    for (int mf = 0; mf < 2; ++mf)
#pragma unroll
        for (int ef = 0; ef < 5; ++ef) acc[mf][ef] = (f32x4){0.f, 0.f, 0.f, 0.f};

    // V-staging registers (T14): loaded for tile 0 in prologue
    const int nl = t >> 2, dc = (t & 3) * 16;
    bf16x8 v0, v1, u0, u1;
    {
        size_t va = rowbase + (size_t)(slice * (N_ / NSPLIT) + nl) * H_ + dc;
        v0 = *(const bf16x8*)(Vh + va);
        v1 = *(const bf16x8*)(Vh + va + 8);
        u0 = *(const bf16x8*)(Vl + va);
        u1 = *(const bf16x8*)(Vl + va + 8);
    }

    for (int tile = 0; tile < 8; ++tile) {
        const int n0 = slice * (N_ / NSPLIT) + tile * 64;
        __syncthreads();   // barrier A: prior GEMM reads of vT done

        // write vT from prefetched regs (transpose V[n][d] -> vT[d][n])
#pragma unroll
        for (int j = 0; j < 8; ++j) {
            vTh[(dc + j) * 72 + nl]     = v0[j];
            vTh[(dc + 8 + j) * 72 + nl] = v1[j];
            vTl[(dc + j) * 72 + nl]     = u0[j];
            vTl[(dc + 8 + j) * 72 + nl] = u1[j];
        }
        if (t < 64) dg[t] = diag_bh[n0 + t] - stab;

        // dash MFMA (global operands, no LDS dependency)
        f32x4 dsh[4][2];
#pragma unroll
        for (int nf = 0; nf < 4; ++nf) {
#pragma unroll
            for (int mf = 0; mf < 2; ++mf) dsh[nf][mf] = (f32x4){0.f, 0.f, 0.f, 0.f};
            bf16x8 ah[2], al[2];
#pragma unroll
            for (int ks = 0; ks < 2; ++ks) {
                size_t ka = rowbase + (size_t)(n0 + nf * 16 + lm) * H_ + ks * 32 + lq * 8;
                ah[ks] = *(const bf16x8*)(Kh + ka);
                al[ks] = *(const bf16x8*)(Kl + ka);
            }
#pragma unroll
            for (int mf = 0; mf < 2; ++mf)
#pragma unroll
                for (int ks = 0; ks < 2; ++ks) {
                    dsh[nf][mf] = __builtin_amdgcn_mfma_f32_16x16x32_bf16(ah[ks], ph[mf][ks], dsh[nf][mf], 0, 0, 0);
                    dsh[nf][mf] = __builtin_amdgcn_mfma_f32_16x16x32_bf16(al[ks], ph[mf][ks], dsh[nf][mf], 0, 0, 0);
                    dsh[nf][mf] = __builtin_amdgcn_mfma_f32_16x16x32_bf16(ah[ks], pl[mf][ks], dsh[nf][mf], 0, 0, 0);
                }
        }

        __syncthreads();   // barrier B: vT + dg staged

        // T14: issue next tile's V loads now (hide under exp + GEMM)
        if (tile < 7) {
            size_t va = rowbase + (size_t)(n0 + 64 + nl) * H_ + dc;
            v0 = *(const bf16x8*)(Vh + va);
            v1 = *(const bf16x8*)(Vh + va + 8);
            u0 = *(const bf16x8*)(Vl + va);
            u1 = *(const bf16x8*)(Vl + va + 8);
        }

        // exp -> kf bf16 hi/lo -> kfT (wave-private rows), b64 writes
#pragma unroll
        for (int nf = 0; nf < 4; ++nf) {
            float4 dgv = *(const float4*)&dg[nf * 16 + lq * 4];
            float dga[4] = {dgv.x, dgv.y, dgv.z, dgv.w};
#pragma unroll
            for (int mf = 0; mf < 2; ++mf) {
                int mrow = w * 32 + mf * 16 + lm;   // block-local m row
                bf16x4 vh_, vl_;
#pragma unroll
                for (int r = 0; r < 4; ++r) {
                    float kf = RATIO * (__expf(dga[r] + NORMALIZER * dsh[nf][mf][r]) + KEPS);
                    __bf16 hh = (__bf16)kf;
                    vh_[r] = hh;
                    vl_[r] = (__bf16)(kf - (float)hh);
                }
                int nbase = nf * 16 + lq * 4;       // multiple of 4 -> 8B aligned
                *(bf16x4*)&kfTh[mrow * 72 + nbase] = vh_;
                *(bf16x4*)&kfTl[mrow * 72 + nbase] = vl_;
            }
        }

        // ctx accumulate: acc[mf][ef] += kfT[m][n] @ vT[e][n]
#pragma unroll
        for (int ks = 0; ks < 2; ++ks) {
#pragma unroll
            for (int mf = 0; mf < 2; ++mf) {
                bf16x8 af = *(const bf16x8*)&kfTh[(w * 32 + mf * 16 + lm) * 72 + ks * 32 + lq * 8];
                bf16x8 afl = *(const bf16x8*)&kfTl[(w * 32 + mf * 16 + lm) * 72 + ks * 32 + lq * 8];
#pragma unroll
                for (int ef = 0; ef < 5; ++ef) {
                    bf16x8 bfh = *(const bf16x8*)&vTh[(ef * 16 + lm) * 72 + ks * 32 + lq * 8];
                    bf16x8 bfl = *(const bf16x8*)&vTl[(ef * 16 + lm) * 72 + ks * 32 + lq * 8];
                    acc[mf][ef] = __builtin_amdgcn_mfma_f32_16x16x32_bf16(af,  bfh, acc[mf][ef], 0, 0, 0);
                    acc[mf][ef] = __builtin_amdgcn_mfma_f32_16x16x32_bf16(afl, bfh, acc[mf][ef], 0, 0, 0);
                    acc[mf][ef] = __builtin_amdgcn_mfma_f32_16x16x32_bf16(af,  bfl, acc[mf][ef], 0, 0, 0);
                }
            }
        }
    }

    // epilogue: acc -> ctxe[m][e] (fp32, pad 81) -> coalesced global [s][bh][e][m]
    __syncthreads();
#pragma unroll
    for (int mf = 0; mf < 2; ++mf)
#pragma unroll
        for (int ef = 0; ef < 5; ++ef)
#pragma unroll
            for (int r = 0; r < 4; ++r) {
                int ml = w * 32 + mf * 16 + lq * 4 + r;
                int e  = ef * 16 + lm;
                ctxe[ml * 81 + e] = acc[mf][ef][r];
            }
    __syncthreads();
    const size_t SLICE = (size_t)(B_ * HEADS_) * EPAD * M_;
    const size_t obase = (size_t)slice * SLICE + (size_t)bh * EPAD * M_;
    for (int i = t; i < EPAD * 128; i += 256) {
        int e = i >> 7, ml = i & 127;
        ctxp[obase + (size_t)e * M_ + mh * 128 + ml] = ctxe[ml * 81 + e];
    }
}

// ======================================================================
// Reduce ctx partials over slices -> bf16 hi/lo ctxT[bh][e][m]
// ======================================================================
__global__ __launch_bounds__(256) void ctx_reduce(
    const float* __restrict__ ctxp, __bf16* __restrict__ ctxTh, __bf16* __restrict__ ctxTl)
{
    int idx = blockIdx.x * 256 + threadIdx.x;     // [0, 32*80*256)
    const size_t SLICE = (size_t)(B_ * HEADS_) * EPAD * M_;
    float s = 0.f;
#pragma unroll
    for (int k = 0; k < NSPLIT; ++k) s += ctxp[(size_t)k * SLICE + idx];
    __bf16 hh = (__bf16)s;
    ctxTh[idx] = hh;
    ctxTl[idx] = (__bf16)(s - (float)hh);
}

// ======================================================================
// out via MFMA. grid (N/128, 32 bh). 4 waves, wave owns 32 n rows (2 nf).
// Restructured for latency: B-side loads (proj per (mf,ks); ctxT per
// (ks,ef)) are shared across the 2 n-fragments -> 2x MFMA per load, 2x
// ILP in dash and out-GEMM chains. No barriers (wave-private LDS).
// ======================================================================
__global__ __launch_bounds__(256) void out_mfma(
    const __bf16* __restrict__ Qh, const __bf16* __restrict__ Ql,
    const __bf16* __restrict__ projH, const __bf16* __restrict__ projL,
    const __bf16* __restrict__ ctxTh, const __bf16* __restrict__ ctxTl,
    __bf16* __restrict__ attnH, __bf16* __restrict__ attnL)
{
    __shared__ alignas(16) __bf16 qfh[4][32][72];
    __shared__ alignas(16) __bf16 qfl[4][32][72];

    const int t    = threadIdx.x;
    const int lane = t & 63;
    const int w    = t >> 6;
    const int lm   = lane & 15;
    const int lq   = lane >> 4;
    const int bh   = blockIdx.y;
    const int b    = bh >> 4, h = bh & 15;
    const int nw   = blockIdx.x * 128 + w * 32;   // wave's n base (32 rows)
    const size_t rowbase = (size_t)b * N_ * H_ + (size_t)h * DH_;

    // A dash frags (q rows), loaded once: [nf][ks]
    bf16x8 qh_[2][2], ql_[2][2];
#pragma unroll
    for (int nf = 0; nf < 2; ++nf)
#pragma unroll
        for (int ks = 0; ks < 2; ++ks) {
            size_t qa = rowbase + (size_t)(nw + nf * 16 + lm) * H_ + ks * 32 + lq * 8;
            qh_[nf][ks] = *(const bf16x8*)(Qh + qa);
            ql_[nf][ks] = *(const bf16x8*)(Ql + qa);
        }

    const __bf16* cth = ctxTh + (size_t)bh * EPAD * M_;
    const __bf16* ctl = ctxTl + (size_t)bh * EPAD * M_;

    f32x4 accO[2][5];
#pragma unroll
    for (int nf = 0; nf < 2; ++nf)
#pragma unroll
        for (int ef = 0; ef < 5; ++ef) accO[nf][ef] = (f32x4){0.f, 0.f, 0.f, 0.f};

    for (int mc = 0; mc < 4; ++mc) {
        const int m0 = mc * 64;
        // dash: proj loaded once per (mf,ks), feeds both nf
        f32x4 dsh[2][4];
#pragma unroll
        for (int nf = 0; nf < 2; ++nf)
#pragma unroll
            for (int mf = 0; mf < 4; ++mf) dsh[nf][mf] = (f32x4){0.f, 0.f, 0.f, 0.f};
#pragma unroll
        for (int mf = 0; mf < 4; ++mf)
#pragma unroll
            for (int ks = 0; ks < 2; ++ks) {
                size_t pa = (size_t)(m0 + mf * 16 + lm) * 64 + ks * 32 + lq * 8;
                bf16x8 ph = *(const bf16x8*)(projH + pa);
                bf16x8 pl = *(const bf16x8*)(projL + pa);
#pragma unroll
                for (int nf = 0; nf < 2; ++nf) {
                    dsh[nf][mf] = __builtin_amdgcn_mfma_f32_16x16x32_bf16(qh_[nf][ks], ph, dsh[nf][mf], 0, 0, 0);
                    dsh[nf][mf] = __builtin_amdgcn_mfma_f32_16x16x32_bf16(ql_[nf][ks], ph, dsh[nf][mf], 0, 0, 0);
                    dsh[nf][mf] = __builtin_amdgcn_mfma_f32_16x16x32_bf16(qh_[nf][ks], pl, dsh[nf][mf], 0, 0, 0);
                }
            }
        // exp -> qf bf16 hi/lo -> wave-private LDS [n32][m64]
#pragma unroll
        for (int nf = 0; nf < 2; ++nf)
#pragma unroll
            for (int mf = 0; mf < 4; ++mf)
#pragma unroll
                for (int r = 0; r < 4; ++r) {
                    float qf = RATIO * (__expf(NORMALIZER * dsh[nf][mf][r]) + KEPS);
                    __bf16 hh = (__bf16)qf;
                    int nloc = nf * 16 + lq * 4 + r;
                    qfh[w][nloc][mf * 16 + lm] = hh;
                    qfl[w][nloc][mf * 16 + lm] = (__bf16)(qf - (float)hh);
                }
        // out GEMM: accO[nf] += qf[n][m] @ ctxT[e][m]; ctxT shared across nf
#pragma unroll
        for (int ks = 0; ks < 2; ++ks) {
            bf16x8 af[2], afl[2];
#pragma unroll
            for (int nf = 0; nf < 2; ++nf) {
                af[nf]  = *(const bf16x8*)&qfh[w][nf * 16 + lm][ks * 32 + lq * 8];
                afl[nf] = *(const bf16x8*)&qfl[w][nf * 16 + lm][ks * 32 + lq * 8];
            }
#pragma unroll
            for (int ef = 0; ef < 5; ++ef) {
                size_t ca = (size_t)(ef * 16 + lm) * M_ + m0 + ks * 32 + lq * 8;
                bf16x8 bfh = *(const bf16x8*)(cth + ca);
                bf16x8 bfl = *(const bf16x8*)(ctl + ca);
#pragma unroll
                for (int nf = 0; nf < 2; ++nf) {
                    accO[nf][ef] = __builtin_amdgcn_mfma_f32_16x16x32_bf16(af[nf],  bfh, accO[nf][ef], 0, 0, 0);
                    accO[nf][ef] = __builtin_amdgcn_mfma_f32_16x16x32_bf16(afl[nf], bfh, accO[nf][ef], 0, 0, 0);
                    accO[nf][ef] = __builtin_amdgcn_mfma_f32_16x16x32_bf16(af[nf],  bfl, accO[nf][ef], 0, 0, 0);
                }
            }
        }
    }

    // denominator + output per nf
#pragma unroll
    for (int nf = 0; nf < 2; ++nf) {
        float dinv[4];
#pragma unroll
        for (int r = 0; r < 4; ++r) {
            float den = __shfl(accO[nf][4][r], lane & 48);
            dinv[r] = 1.f / den;
        }
#pragma unroll
        for (int ef = 0; ef < 4; ++ef)
#pragma unroll
            for (int r = 0; r < 4; ++r) {
                float o = accO[nf][ef][r] * dinv[r];
                __bf16 hh = (__bf16)o;
                size_t oa = rowbase + (size_t)(nw + nf * 16 + lq * 4 + r) * H_ + ef * 16 + lm;
                attnH[oa] = hh;
                attnL[oa] = (__bf16)(o - (float)hh);
            }
    }
}

// ======================================================================
extern "C" void kernel_launch(void* const* d_in, const int* in_sizes, int n_in,
                              void* d_out, int out_size, void* d_ws, size_t ws_size,
                              hipStream_t stream) {
    const float* hs   = (const float*)d_in[0];
    const float* Wq   = (const float*)d_in[1];
    const float* bq   = (const float*)d_in[2];
    const float* Wk   = (const float*)d_in[3];
    const float* bk   = (const float*)d_in[4];
    const float* Wv   = (const float*)d_in[5];
    const float* bv   = (const float*)d_in[6];
    const float* Wo   = (const float*)d_in[7];
    const float* bo   = (const float*)d_in[8];
    const float* proj = (const float*)d_in[9];
    float* out = (float*)d_out;

    const size_t QSZ = (size_t)B_ * N_ * H_;           // 8388608
    const size_t WSZ = (size_t)H_ * H_;                // 1048576
    const size_t CTXT = (size_t)B_ * HEADS_ * EPAD * M_;  // 655360

    __bf16* Qh  = (__bf16*)d_ws;
    __bf16* Ql  = Qh + QSZ;
    __bf16* Kh  = Ql + QSZ;
    __bf16* Kl  = Kh + QSZ;
    __bf16* Vh  = Kl + QSZ;
    __bf16* Vl  = Vh + QSZ;
    __bf16* hsH = Vl + QSZ;      // aliased as attnH after hs consumed
    __bf16* hsL = hsH + QSZ;     // aliased as attnL
    __bf16* WH  = hsL + QSZ;
    __bf16* WL  = WH + 4 * WSZ;
    __bf16* projH = WL + 4 * WSZ;
    __bf16* projL = projH + (size_t)M_ * DH_;
    __bf16* ctxTh = projL + (size_t)M_ * DH_;
    __bf16* ctxTl = ctxTh + CTXT;
    float*  diag  = (float*)(ctxTl + CTXT);
    float*  parts = diag + (size_t)B_ * HEADS_ * N_;
    float*  stab  = parts + 2048;
    float*  ctxp  = stab + 16;

    __bf16 *WqH = WH, *WkH = WH + WSZ, *WvH = WH + 2*WSZ, *WoH = WH + 3*WSZ;
    __bf16 *WqL = WL, *WkL = WL + WSZ, *WvL = WL + 2*WSZ, *WoL = WL + 3*WSZ;

    // 0) splits
    split_bf16<<<QSZ / 4 / 256, 256, 0, stream>>>(hs, hsH, hsL);
    split_w<<<dim3(WSZ / 4 / 256, 4), 256, 0, stream>>>(Wq, Wk, Wv, Wo, WH, WL);
    split_bf16<<<(M_ * DH_) / 4 / 256, 256, 0, stream>>>(proj, projH, projL);

    // 1) Q,K,V = hs @ W^T + b  -> bf16 hi/lo
    gemm_mfma3<true><<<dim3(H_ / 128, (B_ * N_) / 128, 3), 512, 0, stream>>>(
        hsH, hsL, WqH, WqL, WkH, WkL, WvH, WvL, bq, bk, bv,
        nullptr, Qh, Ql, Kh, Kl, Vh, Vl);

    // 2) diag + global stabilizer
    diag_kernel<<<2048, 256, 0, stream>>>(Kh, Kl, diag, parts);
    reduce_stab<<<1, 256, 0, stream>>>(parts, stab, 2048);

    // 3) ctx partials (MFMA)
    ctx_mfma<<<dim3(NSPLIT, 2, B_ * HEADS_), 256, 0, stream>>>(
        Kh, Kl, Vh, Vl, projH, projL, diag, stab, ctxp);

    // 4) reduce partials -> bf16 ctxT
    ctx_reduce<<<(B_ * HEADS_ * EPAD * M_) / 256, 256, 0, stream>>>(ctxp, ctxTh, ctxTl);

    // 5) out (MFMA), writes attn bf16 hi/lo (aliases hs buffers)
    out_mfma<<<dim3(N_ / 128, B_ * HEADS_), 256, 0, stream>>>(
        Qh, Ql, projH, projL, ctxTh, ctxTl, hsH, hsL);

    // 6) final projection fp32 out
    gemm_mfma3<false><<<dim3(H_ / 128, (B_ * N_) / 128, 1), 512, 0, stream>>>(
        hsH, hsL, WoH, WoL, WoH, WoL, WoH, WoL, bo, bo, bo,
        out, nullptr, nullptr, nullptr, nullptr, nullptr, nullptr);
}

// Round 6
// 417.944 us; speedup vs baseline: 1.3013x; 1.0803x over previous
//
#include <hip/hip_runtime.h>
#include <math.h>

#define B_      2
#define N_      4096
#define H_      1024
#define HEADS_  16
#define DH_     64
#define M_      256
#define NSPLIT  8
#define EPAD    80

constexpr float NORMALIZER = 0.35355339059327373f; // 64^-0.25
constexpr float RATIO      = 0.0625f;              // 256^-0.5
constexpr float KEPS       = 1e-3f;

typedef __bf16 bf16x8 __attribute__((ext_vector_type(8)));
typedef __bf16 bf16x4 __attribute__((ext_vector_type(4)));
typedef float  f32x4  __attribute__((ext_vector_type(4)));

// ======================================================================
// Split fp32 -> bf16 (hi, lo)
// ======================================================================
__global__ __launch_bounds__(256) void split_bf16(
    const float* __restrict__ src, __bf16* __restrict__ hi, __bf16* __restrict__ lo)
{
    int i = blockIdx.x * 256 + threadIdx.x;
    float4 v = ((const float4*)src)[i];
    float vv[4] = {v.x, v.y, v.z, v.w};
    bf16x4 h, l;
#pragma unroll
    for (int j = 0; j < 4; ++j) {
        __bf16 hh = (__bf16)vv[j];
        h[j] = hh;
        l[j] = (__bf16)(vv[j] - (float)hh);
    }
    ((bf16x4*)hi)[i] = h;
    ((bf16x4*)lo)[i] = l;
}

__global__ __launch_bounds__(256) void split_w(
    const float* __restrict__ W0, const float* __restrict__ W1,
    const float* __restrict__ W2, const float* __restrict__ W3,
    __bf16* __restrict__ hi, __bf16* __restrict__ lo)
{
    const float* src = W0;
    if (blockIdx.y == 1) src = W1;
    else if (blockIdx.y == 2) src = W2;
    else if (blockIdx.y == 3) src = W3;
    int i = blockIdx.x * 256 + threadIdx.x;
    size_t o = (size_t)blockIdx.y * 262144 + i;
    float4 v = ((const float4*)src)[i];
    float vv[4] = {v.x, v.y, v.z, v.w};
    bf16x4 h, l;
#pragma unroll
    for (int j = 0; j < 4; ++j) {
        __bf16 hh = (__bf16)vv[j];
        h[j] = hh;
        l[j] = (__bf16)(vv[j] - (float)hh);
    }
    ((bf16x4*)hi)[o] = h;
    ((bf16x4*)lo)[o] = l;
}

// ======================================================================
// Split-bf16 MFMA GEMM, C = A@W^T + bias. BF16OUT: write C as bf16 hi/lo.
// Round-2 verified schedule + T1 XCD chunked swizzle (round-4 verified:
// FETCH 407->139 MB, MfmaUtil 49%). UNCHANGED this round.
// ======================================================================
template<bool BF16OUT>
__global__ __launch_bounds__(512, 4) void gemm_mfma3(
    const __bf16* __restrict__ Ah, const __bf16* __restrict__ Al,
    const __bf16* __restrict__ Bh0, const __bf16* __restrict__ Bl0,
    const __bf16* __restrict__ Bh1, const __bf16* __restrict__ Bl1,
    const __bf16* __restrict__ Bh2, const __bf16* __restrict__ Bl2,
    const float* __restrict__ bi0, const float* __restrict__ bi1, const float* __restrict__ bi2,
    float* __restrict__ C0,
    __bf16* __restrict__ Ch0, __bf16* __restrict__ Cl0,
    __bf16* __restrict__ Ch1, __bf16* __restrict__ Cl1,
    __bf16* __restrict__ Ch2, __bf16* __restrict__ Cl2)
{
    const __bf16* Bh = Bh0; const __bf16* Bl = Bl0; const float* bias = bi0;
    __bf16* Ch = Ch0; __bf16* Cl = Cl0;
    if (blockIdx.z == 1) { Bh = Bh1; Bl = Bl1; bias = bi1; Ch = Ch1; Cl = Cl1; }
    else if (blockIdx.z == 2) { Bh = Bh2; Bl = Bl2; bias = bi2; Ch = Ch2; Cl = Cl2; }

    // [buf][tile][128*32] linear; tile: 0=Ah 1=Al 2=Bh 3=Bl
    __shared__ alignas(16) __bf16 lds[2][4][128 * 32];

    const int t    = threadIdx.x;
    const int lane = t & 63;
    const int lm   = lane & 15;
    const int lq   = lane >> 4;
    const int w    = t >> 6;
    const int wm   = (w >> 2) * 64;    // m half
    const int wn   = (w & 3) * 32;     // n quarter

    // T1 XCD chunked swizzle (bijective: 512 % 8 == 0)
    const int wg = blockIdx.x + 8 * blockIdx.y;   // hardware-linear within z
    const int sw = (wg & 7) * 64 + (wg >> 3);
    const int n0 = (sw & 7) * 128;
    const int m0 = (sw >> 3) * 128;
    const int K    = 1024;
    const int NK   = 32;

    const int tw = w >> 1;
    const int hw = w & 1;
    const __bf16* mysrc = (tw == 0) ? Ah : (tw == 1) ? Al : (tw == 2) ? Bh : Bl;
    const int     rbase = ((tw < 2) ? m0 : n0) + hw * 64;
    const int rsub   = lane >> 2;
    const int slot   = lane & 3;
    const int schunk = slot ^ ((lane >> 3) & 3);
    const __bf16* gbase = mysrc + (size_t)(rbase + rsub) * K + schunk * 8;

    f32x4 acc[4][2];
#pragma unroll
    for (int i = 0; i < 4; ++i)
#pragma unroll
        for (int j = 0; j < 2; ++j) acc[i][j] = (f32x4){0.f, 0.f, 0.f, 0.f};

    // read-side swizzle (same involution, lane-constant)
    const int swz = (lq ^ ((lm >> 1) & 3)) * 8;

    auto stage = [&](int buf, int k0) {
#pragma unroll
        for (int c = 0; c < 4; ++c) {
            const __bf16* g = gbase + (size_t)c * 16 * K + k0;
            __builtin_amdgcn_global_load_lds(
                (const __attribute__((address_space(1))) void*)g,
                (__attribute__((address_space(3))) void*)&lds[buf][tw][(hw * 64 + c * 16) * 32],
                16, 0, 0);
        }
    };

    auto compute = [&](int p) {
        const __bf16* tAh = lds[p][0];
        const __bf16* tAl = lds[p][1];
        const __bf16* tBh = lds[p][2];
        const __bf16* tBl = lds[p][3];
        bf16x8 bh[2], bl[2];
#pragma unroll
        for (int j = 0; j < 2; ++j) {
            int off = (wn + j * 16 + lm) * 32 + swz;
            bh[j] = *(const bf16x8*)&tBh[off];
            bl[j] = *(const bf16x8*)&tBl[off];
        }
#pragma unroll
        for (int i = 0; i < 4; ++i) {
            int off = (wm + i * 16 + lm) * 32 + swz;
            bf16x8 ah = *(const bf16x8*)&tAh[off];
            bf16x8 al = *(const bf16x8*)&tAl[off];
#pragma unroll
            for (int j = 0; j < 2; ++j) {
                acc[i][j] = __builtin_amdgcn_mfma_f32_16x16x32_bf16(ah, bh[j], acc[i][j], 0, 0, 0);
                acc[i][j] = __builtin_amdgcn_mfma_f32_16x16x32_bf16(al, bh[j], acc[i][j], 0, 0, 0);
                acc[i][j] = __builtin_amdgcn_mfma_f32_16x16x32_bf16(ah, bl[j], acc[i][j], 0, 0, 0);
            }
        }
    };

    stage(0, 0);
    int p = 0;
#pragma unroll 1
    for (int kk = 0; kk < NK - 1; ++kk) {
        stage(p ^ 1, (kk + 1) * 32);
        asm volatile("s_waitcnt vmcnt(4)" ::: "memory");
        asm volatile("s_barrier" ::: "memory");
        compute(p);
        asm volatile("s_barrier" ::: "memory");
        p ^= 1;
    }
    asm volatile("s_waitcnt vmcnt(0)" ::: "memory");
    asm volatile("s_barrier" ::: "memory");
    compute(p);

    float bsr[2];
#pragma unroll
    for (int j = 0; j < 2; ++j) bsr[j] = bias[n0 + wn + j * 16 + lm];
#pragma unroll
    for (int i = 0; i < 4; ++i)
#pragma unroll
        for (int r = 0; r < 4; ++r) {
            int rowm = m0 + wm + i * 16 + lq * 4 + r;
#pragma unroll
            for (int j = 0; j < 2; ++j) {
                int col = n0 + wn + j * 16 + lm;
                float o = acc[i][j][r] + bsr[j];
                if (BF16OUT) {
                    __bf16 hh = (__bf16)o;
                    Ch[(size_t)rowm * 1024 + col] = hh;
                    Cl[(size_t)rowm * 1024 + col] = (__bf16)(o - (float)hh);
                } else {
                    C0[(size_t)rowm * 1024 + col] = o;
                }
            }
        }
}

// ======================================================================
// diag_k from bf16 hi/lo K
// ======================================================================
__global__ __launch_bounds__(256) void diag_kernel(
    const __bf16* __restrict__ Kh, const __bf16* __restrict__ Kl,
    float* __restrict__ diag, float* __restrict__ partials)
{
    int gt = blockIdx.x * 256 + threadIdx.x;
    int r  = gt >> 2;
    int q  = gt & 3;
    const bf16x8* ph = (const bf16x8*)(Kh + (size_t)r * 64 + q * 16);
    const bf16x8* pl = (const bf16x8*)(Kl + (size_t)r * 64 + q * 16);
    float s = 0.f;
#pragma unroll
    for (int i = 0; i < 2; ++i) {
        bf16x8 vh = ph[i], vl = pl[i];
#pragma unroll
        for (int j = 0; j < 8; ++j) {
            float x = (float)vh[j] + (float)vl[j];
            s += x * x;
        }
    }
    s += __shfl_xor(s, 1);
    s += __shfl_xor(s, 2);
    float d = -0.5f * s;
    if (q == 0) {
        int h = r & 15, bn = r >> 4;
        int n = bn & 4095, b = bn >> 12;
        diag[(((size_t)b * 16 + h) << 12) + n] = d;
    }
    __shared__ float red[256];
    red[threadIdx.x] = d;
    __syncthreads();
    for (int s2 = 128; s2 > 0; s2 >>= 1) {
        if (threadIdx.x < s2) red[threadIdx.x] = fmaxf(red[threadIdx.x], red[threadIdx.x + s2]);
        __syncthreads();
    }
    if (threadIdx.x == 0) partials[blockIdx.x] = red[0];
}

__global__ __launch_bounds__(256) void reduce_stab(
    const float* __restrict__ partials, float* __restrict__ stab, int n)
{
    float m = -3.0e38f;
    for (int i = threadIdx.x; i < n; i += 256) m = fmaxf(m, partials[i]);
    __shared__ float red[256];
    red[threadIdx.x] = m;
    __syncthreads();
    for (int s2 = 128; s2 > 0; s2 >>= 1) {
        if (threadIdx.x < s2) red[threadIdx.x] = fmaxf(red[threadIdx.x], red[threadIdx.x + s2]);
        __syncthreads();
    }
    if (threadIdx.x == 0) stab[0] = red[0];
}

// ======================================================================
// ctx via MFMA. grid (NSPLIT, 2 m-halves, 32 bh). 4 waves, wave owns 32 m.
// T14 async-STAGE split for BOTH V and K: next tile's V and K loads issue
// right after barrier B (hidden under exp + ctx-GEMM, ~2500 cyc); dash
// consumes register-prefetched K -> no exposed global latency after
// barrier A. launch_bounds(256,2) caps VGPR at 256 (est ~225, no spill).
// ======================================================================
__global__ __launch_bounds__(256, 2) void ctx_mfma(
    const __bf16* __restrict__ Kh, const __bf16* __restrict__ Kl,
    const __bf16* __restrict__ Vh, const __bf16* __restrict__ Vl,
    const __bf16* __restrict__ projH, const __bf16* __restrict__ projL,
    const float* __restrict__ diag, const float* __restrict__ stabp,
    float* __restrict__ ctxp)
{
    __shared__ alignas(16) char ldsbuf[59904];
    __shared__ float dg[64];
    __bf16* kfTh = (__bf16*)ldsbuf;              // [128][72]
    __bf16* kfTl = kfTh + 9216;                  // [128][72]
    __bf16* vTh  = kfTl + 9216;                  // [80][72]
    __bf16* vTl  = vTh + 5760;                   // [80][72]
    float*  ctxe = (float*)ldsbuf;               // [128][81] (epilogue alias)

    const int t    = threadIdx.x;
    const int lane = t & 63;
    const int w    = t >> 6;
    const int lm   = lane & 15;
    const int lq   = lane >> 4;
    const int bh   = blockIdx.z;
    const int b    = bh >> 4, h = bh & 15;
    const int mh   = blockIdx.y;
    const int slice = blockIdx.x;
    const int mwave = mh * 128 + w * 32;          // global m base for wave
    const float stab = stabp[0];
    const size_t rowbase = (size_t)b * N_ * H_ + (size_t)h * DH_;
    const float* diag_bh = diag + (size_t)bh * N_;

    // vT constant rows: e=64 -> ones (hi), e>64 -> zero
    for (int idx = t; idx < 16 * 72; idx += 256) {
        int e = 64 + idx / 72, n = idx % 72;
        vTh[e * 72 + n] = (e == 64 && n < 64) ? (__bf16)1.0f : (__bf16)0.0f;
        vTl[e * 72 + n] = (__bf16)0.0f;
    }

    // proj B-frags, register-cached for whole kernel: [mf][ks]
    bf16x8 ph[2][2], pl[2][2];
#pragma unroll
    for (int mf = 0; mf < 2; ++mf)
#pragma unroll
        for (int ks = 0; ks < 2; ++ks) {
            size_t pa = (size_t)(mwave + mf * 16 + lm) * 64 + ks * 32 + lq * 8;
            ph[mf][ks] = *(const bf16x8*)(projH + pa);
            pl[mf][ks] = *(const bf16x8*)(projL + pa);
        }

    f32x4 acc[2][5];
#pragma unroll
    for (int mf = 0; mf < 2; ++mf)
#pragma unroll
        for (int ef = 0; ef < 5; ++ef) acc[mf][ef] = (f32x4){0.f, 0.f, 0.f, 0.f};

    // prefetch regs (T14): V transpose rows + K dash frags, tile 0
    const int nl = t >> 2, dc = (t & 3) * 16;
    bf16x8 v0, v1, u0, u1;
    bf16x8 kh_p[4][2], kl_p[4][2];
    {
        const int nbase = slice * (N_ / NSPLIT);
        size_t va = rowbase + (size_t)(nbase + nl) * H_ + dc;
        v0 = *(const bf16x8*)(Vh + va);
        v1 = *(const bf16x8*)(Vh + va + 8);
        u0 = *(const bf16x8*)(Vl + va);
        u1 = *(const bf16x8*)(Vl + va + 8);
#pragma unroll
        for (int nf = 0; nf < 4; ++nf)
#pragma unroll
            for (int ks = 0; ks < 2; ++ks) {
                size_t ka = rowbase + (size_t)(nbase + nf * 16 + lm) * H_ + ks * 32 + lq * 8;
                kh_p[nf][ks] = *(const bf16x8*)(Kh + ka);
                kl_p[nf][ks] = *(const bf16x8*)(Kl + ka);
            }
    }

    for (int tile = 0; tile < 8; ++tile) {
        const int n0 = slice * (N_ / NSPLIT) + tile * 64;
        __syncthreads();   // barrier A: prior GEMM reads of vT done

        // write vT from prefetched regs (transpose V[n][d] -> vT[d][n])
#pragma unroll
        for (int j = 0; j < 8; ++j) {
            vTh[(dc + j) * 72 + nl]     = v0[j];
            vTh[(dc + 8 + j) * 72 + nl] = v1[j];
            vTl[(dc + j) * 72 + nl]     = u0[j];
            vTl[(dc + 8 + j) * 72 + nl] = u1[j];
        }
        if (t < 64) dg[t] = diag_bh[n0 + t] - stab;

        // dash MFMA from register-prefetched K (no global latency here)
        f32x4 dsh[4][2];
#pragma unroll
        for (int nf = 0; nf < 4; ++nf) {
#pragma unroll
            for (int mf = 0; mf < 2; ++mf) dsh[nf][mf] = (f32x4){0.f, 0.f, 0.f, 0.f};
#pragma unroll
            for (int mf = 0; mf < 2; ++mf)
#pragma unroll
                for (int ks = 0; ks < 2; ++ks) {
                    dsh[nf][mf] = __builtin_amdgcn_mfma_f32_16x16x32_bf16(kh_p[nf][ks], ph[mf][ks], dsh[nf][mf], 0, 0, 0);
                    dsh[nf][mf] = __builtin_amdgcn_mfma_f32_16x16x32_bf16(kl_p[nf][ks], ph[mf][ks], dsh[nf][mf], 0, 0, 0);
                    dsh[nf][mf] = __builtin_amdgcn_mfma_f32_16x16x32_bf16(kh_p[nf][ks], pl[mf][ks], dsh[nf][mf], 0, 0, 0);
                }
        }

        __syncthreads();   // barrier B: vT + dg staged

        // T14: issue next tile's V and K loads now (hide under exp + GEMM)
        if (tile < 7) {
            size_t va = rowbase + (size_t)(n0 + 64 + nl) * H_ + dc;
            v0 = *(const bf16x8*)(Vh + va);
            v1 = *(const bf16x8*)(Vh + va + 8);
            u0 = *(const bf16x8*)(Vl + va);
            u1 = *(const bf16x8*)(Vl + va + 8);
#pragma unroll
            for (int nf = 0; nf < 4; ++nf)
#pragma unroll
                for (int ks = 0; ks < 2; ++ks) {
                    size_t ka = rowbase + (size_t)(n0 + 64 + nf * 16 + lm) * H_ + ks * 32 + lq * 8;
                    kh_p[nf][ks] = *(const bf16x8*)(Kh + ka);
                    kl_p[nf][ks] = *(const bf16x8*)(Kl + ka);
                }
        }

        // exp -> kf bf16 hi/lo -> kfT (wave-private rows), b64 writes
#pragma unroll
        for (int nf = 0; nf < 4; ++nf) {
            float4 dgv = *(const float4*)&dg[nf * 16 + lq * 4];
            float dga[4] = {dgv.x, dgv.y, dgv.z, dgv.w};
#pragma unroll
            for (int mf = 0; mf < 2; ++mf) {
                int mrow = w * 32 + mf * 16 + lm;   // block-local m row
                bf16x4 vh_, vl_;
#pragma unroll
                for (int r = 0; r < 4; ++r) {
                    float kf = RATIO * (__expf(dga[r] + NORMALIZER * dsh[nf][mf][r]) + KEPS);
                    __bf16 hh = (__bf16)kf;
                    vh_[r] = hh;
                    vl_[r] = (__bf16)(kf - (float)hh);
                }
                int nbase = nf * 16 + lq * 4;       // multiple of 4 -> 8B aligned
                *(bf16x4*)&kfTh[mrow * 72 + nbase] = vh_;
                *(bf16x4*)&kfTl[mrow * 72 + nbase] = vl_;
            }
        }

        // ctx accumulate: acc[mf][ef] += kfT[m][n] @ vT[e][n]
#pragma unroll
        for (int ks = 0; ks < 2; ++ks) {
#pragma unroll
            for (int mf = 0; mf < 2; ++mf) {
                bf16x8 af = *(const bf16x8*)&kfTh[(w * 32 + mf * 16 + lm) * 72 + ks * 32 + lq * 8];
                bf16x8 afl = *(const bf16x8*)&kfTl[(w * 32 + mf * 16 + lm) * 72 + ks * 32 + lq * 8];
#pragma unroll
                for (int ef = 0; ef < 5; ++ef) {
                    bf16x8 bfh = *(const bf16x8*)&vTh[(ef * 16 + lm) * 72 + ks * 32 + lq * 8];
                    bf16x8 bfl = *(const bf16x8*)&vTl[(ef * 16 + lm) * 72 + ks * 32 + lq * 8];
                    acc[mf][ef] = __builtin_amdgcn_mfma_f32_16x16x32_bf16(af,  bfh, acc[mf][ef], 0, 0, 0);
                    acc[mf][ef] = __builtin_amdgcn_mfma_f32_16x16x32_bf16(afl, bfh, acc[mf][ef], 0, 0, 0);
                    acc[mf][ef] = __builtin_amdgcn_mfma_f32_16x16x32_bf16(af,  bfl, acc[mf][ef], 0, 0, 0);
                }
            }
        }
    }

    // epilogue: acc -> ctxe[m][e] (fp32, pad 81) -> coalesced global [s][bh][e][m]
    __syncthreads();
#pragma unroll
    for (int mf = 0; mf < 2; ++mf)
#pragma unroll
        for (int ef = 0; ef < 5; ++ef)
#pragma unroll
            for (int r = 0; r < 4; ++r) {
                int ml = w * 32 + mf * 16 + lq * 4 + r;
                int e  = ef * 16 + lm;
                ctxe[ml * 81 + e] = acc[mf][ef][r];
            }
    __syncthreads();
    const size_t SLICE = (size_t)(B_ * HEADS_) * EPAD * M_;
    const size_t obase = (size_t)slice * SLICE + (size_t)bh * EPAD * M_;
    for (int i = t; i < EPAD * 128; i += 256) {
        int e = i >> 7, ml = i & 127;
        ctxp[obase + (size_t)e * M_ + mh * 128 + ml] = ctxe[ml * 81 + e];
    }
}

// ======================================================================
// Reduce ctx partials over slices -> bf16 hi/lo ctxT[bh][e][m]
// ======================================================================
__global__ __launch_bounds__(256) void ctx_reduce(
    const float* __restrict__ ctxp, __bf16* __restrict__ ctxTh, __bf16* __restrict__ ctxTl)
{
    int idx = blockIdx.x * 256 + threadIdx.x;     // [0, 32*80*256)
    const size_t SLICE = (size_t)(B_ * HEADS_) * EPAD * M_;
    float s = 0.f;
#pragma unroll
    for (int k = 0; k < NSPLIT; ++k) s += ctxp[(size_t)k * SLICE + idx];
    __bf16 hh = (__bf16)s;
    ctxTh[idx] = hh;
    ctxTl[idx] = (__bf16)(s - (float)hh);
}

// ======================================================================
// out via MFMA. grid (N/256, 32 bh). 512 thr / 8 waves, wave owns 32 n.
// ctxT (block-shared, 80x256 hi+lo) is staged ONCE into LDS via
// global_load_lds with source-side XOR swizzle (chunk ^= row&7, rule #21)
// -> out-GEMM B-operands are ~12-cyc LDS reads instead of ~300-900 cyc
// global reads repeated per wave per mc. Only global traffic in the mc
// loop is the small L2-hot proj. LDS: qf 72KB + ctx 80KB = 152KB, 1 blk/CU.
// ======================================================================
__global__ __launch_bounds__(512, 2) void out_mfma(
    const __bf16* __restrict__ Qh, const __bf16* __restrict__ Ql,
    const __bf16* __restrict__ projH, const __bf16* __restrict__ projL,
    const __bf16* __restrict__ ctxTh, const __bf16* __restrict__ ctxTl,
    __bf16* __restrict__ attnH, __bf16* __restrict__ attnL)
{
    __shared__ alignas(16) __bf16 ctxLh[80 * 256];   // [e][m], 16B-chunk swizzled
    __shared__ alignas(16) __bf16 ctxLl[80 * 256];
    __shared__ alignas(16) __bf16 qfh[8][32][72];
    __shared__ alignas(16) __bf16 qfl[8][32][72];

    const int t    = threadIdx.x;
    const int lane = t & 63;
    const int w    = t >> 6;                      // 0..7
    const int lm   = lane & 15;
    const int lq   = lane >> 4;
    const int bh   = blockIdx.y;
    const int b    = bh >> 4, h = bh & 15;
    const int nw   = blockIdx.x * 256 + w * 32;   // wave's n base (32 rows)
    const size_t rowbase = (size_t)b * N_ * H_ + (size_t)h * DH_;

    const __bf16* cth = ctxTh + (size_t)bh * EPAD * M_;
    const __bf16* ctl = ctxTl + (size_t)bh * EPAD * M_;

    // stage ctxT -> LDS. LDS slot (row, cp) holds global 16B-chunk
    // cp ^ (row & 7) (linear dest + inverse-swizzled source, rule #21).
    {
        const int r_in = lane >> 5;               // 0..1 (row within 1KiB)
        const int cp   = lane & 31;               // chunk slot within row
#pragma unroll
        for (int c = 0; c < 5; ++c) {
            int idx = w * 5 + c;                  // 1KiB chunk id 0..39
            int r   = idx * 2 + r_in;             // row 0..79
            int gc  = cp ^ (r & 7);
            const __bf16* gh = cth + (size_t)r * 256 + gc * 8;
            const __bf16* gl = ctl + (size_t)r * 256 + gc * 8;
            __builtin_amdgcn_global_load_lds(
                (const __attribute__((address_space(1))) void*)gh,
                (__attribute__((address_space(3))) void*)&ctxLh[idx * 512],
                16, 0, 0);
            __builtin_amdgcn_global_load_lds(
                (const __attribute__((address_space(1))) void*)gl,
                (__attribute__((address_space(3))) void*)&ctxLl[idx * 512],
                16, 0, 0);
        }
    }

    // A dash frags (q rows), loaded while staging is in flight: [nf][ks]
    bf16x8 qh_[2][2], ql_[2][2];
#pragma unroll
    for (int nf = 0; nf < 2; ++nf)
#pragma unroll
        for (int ks = 0; ks < 2; ++ks) {
            size_t qa = rowbase + (size_t)(nw + nf * 16 + lm) * H_ + ks * 32 + lq * 8;
            qh_[nf][ks] = *(const bf16x8*)(Qh + qa);
            ql_[nf][ks] = *(const bf16x8*)(Ql + qa);
        }

    __syncthreads();   // ctx staged (drains vmcnt)

    f32x4 accO[2][5];
#pragma unroll
    for (int nf = 0; nf < 2; ++nf)
#pragma unroll
        for (int ef = 0; ef < 5; ++ef) accO[nf][ef] = (f32x4){0.f, 0.f, 0.f, 0.f};

#pragma unroll
    for (int mc = 0; mc < 4; ++mc) {
        const int m0 = mc * 64;
        // dash: proj loaded once per (mf,ks), feeds both nf
        f32x4 dsh[2][4];
#pragma unroll
        for (int nf = 0; nf < 2; ++nf)
#pragma unroll
            for (int mf = 0; mf < 4; ++mf) dsh[nf][mf] = (f32x4){0.f, 0.f, 0.f, 0.f};
#pragma unroll
        for (int mf = 0; mf < 4; ++mf)
#pragma unroll
            for (int ks = 0; ks < 2; ++ks) {
                size_t pa = (size_t)(m0 + mf * 16 + lm) * 64 + ks * 32 + lq * 8;
                bf16x8 ph = *(const bf16x8*)(projH + pa);
                bf16x8 pl = *(const bf16x8*)(projL + pa);
#pragma unroll
                for (int nf = 0; nf < 2; ++nf) {
                    dsh[nf][mf] = __builtin_amdgcn_mfma_f32_16x16x32_bf16(qh_[nf][ks], ph, dsh[nf][mf], 0, 0, 0);
                    dsh[nf][mf] = __builtin_amdgcn_mfma_f32_16x16x32_bf16(ql_[nf][ks], ph, dsh[nf][mf], 0, 0, 0);
                    dsh[nf][mf] = __builtin_amdgcn_mfma_f32_16x16x32_bf16(qh_[nf][ks], pl, dsh[nf][mf], 0, 0, 0);
                }
            }
        // exp -> qf bf16 hi/lo -> wave-private LDS [n32][m64]
#pragma unroll
        for (int nf = 0; nf < 2; ++nf)
#pragma unroll
            for (int mf = 0; mf < 4; ++mf)
#pragma unroll
                for (int r = 0; r < 4; ++r) {
                    float qf = RATIO * (__expf(NORMALIZER * dsh[nf][mf][r]) + KEPS);
                    __bf16 hh = (__bf16)qf;
                    int nloc = nf * 16 + lq * 4 + r;
                    qfh[w][nloc][mf * 16 + lm] = hh;
                    qfl[w][nloc][mf * 16 + lm] = (__bf16)(qf - (float)hh);
                }
        // out GEMM: accO[nf] += qf[n][m] @ ctxLDS[e][m]; B shared across nf
#pragma unroll
        for (int ks = 0; ks < 2; ++ks) {
            bf16x8 af[2], afl[2];
#pragma unroll
            for (int nf = 0; nf < 2; ++nf) {
                af[nf]  = *(const bf16x8*)&qfh[w][nf * 16 + lm][ks * 32 + lq * 8];
                afl[nf] = *(const bf16x8*)&qfl[w][nf * 16 + lm][ks * 32 + lq * 8];
            }
#pragma unroll
            for (int ef = 0; ef < 5; ++ef) {
                int row = ef * 16 + lm;
                int sc  = ((m0 >> 3) + ks * 4 + lq) ^ (lm & 7);   // swizzled chunk
                int off = row * 256 + sc * 8;
                bf16x8 bfh = *(const bf16x8*)&ctxLh[off];
                bf16x8 bfl = *(const bf16x8*)&ctxLl[off];
#pragma unroll
                for (int nf = 0; nf < 2; ++nf) {
                    accO[nf][ef] = __builtin_amdgcn_mfma_f32_16x16x32_bf16(af[nf],  bfh, accO[nf][ef], 0, 0, 0);
                    accO[nf][ef] = __builtin_amdgcn_mfma_f32_16x16x32_bf16(afl[nf], bfh, accO[nf][ef], 0, 0, 0);
                    accO[nf][ef] = __builtin_amdgcn_mfma_f32_16x16x32_bf16(af[nf],  bfl, accO[nf][ef], 0, 0, 0);
                }
            }
        }
    }

    // denominator + output per nf
#pragma unroll
    for (int nf = 0; nf < 2; ++nf) {
        float dinv[4];
#pragma unroll
        for (int r = 0; r < 4; ++r) {
            float den = __shfl(accO[nf][4][r], lane & 48);
            dinv[r] = 1.f / den;
        }
#pragma unroll
        for (int ef = 0; ef < 4; ++ef)
#pragma unroll
            for (int r = 0; r < 4; ++r) {
                float o = accO[nf][ef][r] * dinv[r];
                __bf16 hh = (__bf16)o;
                size_t oa = rowbase + (size_t)(nw + nf * 16 + lq * 4 + r) * H_ + ef * 16 + lm;
                attnH[oa] = hh;
                attnL[oa] = (__bf16)(o - (float)hh);
            }
    }
}

// ======================================================================
extern "C" void kernel_launch(void* const* d_in, const int* in_sizes, int n_in,
                              void* d_out, int out_size, void* d_ws, size_t ws_size,
                              hipStream_t stream) {
    const float* hs   = (const float*)d_in[0];
    const float* Wq   = (const float*)d_in[1];
    const float* bq   = (const float*)d_in[2];
    const float* Wk   = (const float*)d_in[3];
    const float* bk   = (const float*)d_in[4];
    const float* Wv   = (const float*)d_in[5];
    const float* bv   = (const float*)d_in[6];
    const float* Wo   = (const float*)d_in[7];
    const float* bo   = (const float*)d_in[8];
    const float* proj = (const float*)d_in[9];
    float* out = (float*)d_out;

    const size_t QSZ = (size_t)B_ * N_ * H_;           // 8388608
    const size_t WSZ = (size_t)H_ * H_;                // 1048576
    const size_t CTXT = (size_t)B_ * HEADS_ * EPAD * M_;  // 655360

    __bf16* Qh  = (__bf16*)d_ws;
    __bf16* Ql  = Qh + QSZ;
    __bf16* Kh  = Ql + QSZ;
    __bf16* Kl  = Kh + QSZ;
    __bf16* Vh  = Kl + QSZ;
    __bf16* Vl  = Vh + QSZ;
    __bf16* hsH = Vl + QSZ;      // aliased as attnH after hs consumed
    __bf16* hsL = hsH + QSZ;     // aliased as attnL
    __bf16* WH  = hsL + QSZ;
    __bf16* WL  = WH + 4 * WSZ;
    __bf16* projH = WL + 4 * WSZ;
    __bf16* projL = projH + (size_t)M_ * DH_;
    __bf16* ctxTh = projL + (size_t)M_ * DH_;
    __bf16* ctxTl = ctxTh + CTXT;
    float*  diag  = (float*)(ctxTl + CTXT);
    float*  parts = diag + (size_t)B_ * HEADS_ * N_;
    float*  stab  = parts + 2048;
    float*  ctxp  = stab + 16;

    __bf16 *WqH = WH, *WkH = WH + WSZ, *WvH = WH + 2*WSZ, *WoH = WH + 3*WSZ;
    __bf16 *WqL = WL, *WkL = WL + WSZ, *WvL = WL + 2*WSZ, *WoL = WL + 3*WSZ;

    // 0) splits
    split_bf16<<<QSZ / 4 / 256, 256, 0, stream>>>(hs, hsH, hsL);
    split_w<<<dim3(WSZ / 4 / 256, 4), 256, 0, stream>>>(Wq, Wk, Wv, Wo, WH, WL);
    split_bf16<<<(M_ * DH_) / 4 / 256, 256, 0, stream>>>(proj, projH, projL);

    // 1) Q,K,V = hs @ W^T + b  -> bf16 hi/lo
    gemm_mfma3<true><<<dim3(H_ / 128, (B_ * N_) / 128, 3), 512, 0, stream>>>(
        hsH, hsL, WqH, WqL, WkH, WkL, WvH, WvL, bq, bk, bv,
        nullptr, Qh, Ql, Kh, Kl, Vh, Vl);

    // 2) diag + global stabilizer
    diag_kernel<<<2048, 256, 0, stream>>>(Kh, Kl, diag, parts);
    reduce_stab<<<1, 256, 0, stream>>>(parts, stab, 2048);

    // 3) ctx partials (MFMA)
    ctx_mfma<<<dim3(NSPLIT, 2, B_ * HEADS_), 256, 0, stream>>>(
        Kh, Kl, Vh, Vl, projH, projL, diag, stab, ctxp);

    // 4) reduce partials -> bf16 ctxT
    ctx_reduce<<<(B_ * HEADS_ * EPAD * M_) / 256, 256, 0, stream>>>(ctxp, ctxTh, ctxTl);

    // 5) out (MFMA), 512 thr / 8 waves, ctxT staged in LDS
    out_mfma<<<dim3(N_ / 256, B_ * HEADS_), 512, 0, stream>>>(
        Qh, Ql, projH, projL, ctxTh, ctxTl, hsH, hsL);

    // 6) final projection fp32 out
    gemm_mfma3<false><<<dim3(H_ / 128, (B_ * N_) / 128, 1), 512, 0, stream>>>(
        hsH, hsL, WoH, WoL, WoH, WoL, WoH, WoL, bo, bo, bo,
        out, nullptr, nullptr, nullptr, nullptr, nullptr, nullptr);
}